// Round 5
// baseline (422.494 us; speedup 1.0000x reference)
//
#include <hip/hip_runtime.h>
#include <math.h>

#define B_ 4
#define N_ 1024
#define C_ 512
#define H_ 8
#define HD_ 64
#define SCALE_ 0.125f
#define LN_EPS_ 1e-5f

typedef _Float16 f16x8 __attribute__((ext_vector_type(8)));
typedef float f32x4 __attribute__((ext_vector_type(4)));

// Split 8 fp32 (two float4) into f16 hi + f16 lo such that hi+lo ~= x (22-bit).
__device__ __forceinline__ void cvt_split(const float4& A, const float4& Bv,
                                          f16x8& hi, f16x8& lo) {
    float v[8] = {A.x, A.y, A.z, A.w, Bv.x, Bv.y, Bv.z, Bv.w};
#pragma unroll
    for (int i = 0; i < 8; ++i) {
        _Float16 h = (_Float16)v[i];
        hi[i] = h;
        lo[i] = (_Float16)(v[i] - (float)h);
    }
}

// ---------------------------------------------------------------------------
// Kernel 0: wsplit_qkv — transpose + f16-split Wqkv [512][1536] into
//   Wt_hi/Wt_lo [1536][512] (row = output column, k contiguous).
//   Output lives in the attn region (rewritten later by attn_scores).
// ---------------------------------------------------------------------------
__global__ __launch_bounds__(256) void wsplit_qkv(const float* __restrict__ W,
                                                  _Float16* __restrict__ wt_hi,
                                                  _Float16* __restrict__ wt_lo) {
    __shared__ float tile[64][65];
    const int tid = threadIdx.x;
    const int n0 = blockIdx.x * 64;   // col of W  (row of Wt)
    const int k0 = blockIdx.y * 64;   // row of W  (col of Wt)
#pragma unroll
    for (int i = 0; i < 16; ++i) {
        int e = tid + i * 256;
        int kk = e >> 6, nn = e & 63;
        tile[kk][nn] = W[(size_t)(k0 + kk) * (3 * C_) + n0 + nn];
    }
    __syncthreads();
#pragma unroll
    for (int i = 0; i < 16; ++i) {
        int e = tid + i * 256;
        int n = e >> 6, k = e & 63;
        float v = tile[k][n];
        _Float16 h = (_Float16)v;
        wt_hi[(size_t)(n0 + n) * C_ + k0 + k] = h;
        wt_lo[(size_t)(n0 + n) * C_ + k0 + k] = (_Float16)(v - (float)h);
    }
}

// ---------------------------------------------------------------------------
// Kernel 0b: vsplit_v — transpose + f16-split V (from qkv) into
//   Vt_hi/Vt_lo [B*H][HD][N] (m contiguous). Lives in the y region of out
//   (8 MB exactly), which proj_gemm rewrites after pv_mfma consumes it.
// ---------------------------------------------------------------------------
__global__ __launch_bounds__(256) void vsplit_v(const float* __restrict__ qkv,
                                                _Float16* __restrict__ vt_hi,
                                                _Float16* __restrict__ vt_lo) {
    __shared__ float tile[64][65];
    const int tid = threadIdx.x;
    const int m0 = blockIdx.x * 64;
    const int bh = blockIdx.y;
    const int b = bh >> 3, h = bh & 7;
    const size_t RS = 3 * C_;
#pragma unroll
    for (int i = 0; i < 16; ++i) {
        int e = tid + i * 256;
        int mm = e >> 6, d = e & 63;
        tile[mm][d] = qkv[(size_t)(b * N_ + m0 + mm) * RS + 2 * C_ + h * HD_ + d];
    }
    __syncthreads();
#pragma unroll
    for (int i = 0; i < 16; ++i) {
        int e = tid + i * 256;
        int d = e >> 6, mm = e & 63;
        float v = tile[mm][d];
        _Float16 hh = (_Float16)v;
        size_t idx = ((size_t)bh * HD_ + d) * N_ + m0 + mm;
        vt_hi[idx] = hh;
        vt_lo[idx] = (_Float16)(v - (float)hh);
    }
}

// ---------------------------------------------------------------------------
// Kernel 1: qkv_gemm_mfma (unchanged — validated round 3)
// ---------------------------------------------------------------------------
__global__ __launch_bounds__(256) void qkv_gemm_mfma(const float* __restrict__ x,
                                                     const _Float16* __restrict__ wt_hi,
                                                     const _Float16* __restrict__ wt_lo,
                                                     const float* __restrict__ bqkv,
                                                     float* __restrict__ qkv) {
    const int tid = threadIdx.x;
    const int lane = tid & 63;
    const int w = tid >> 6;
    const int r16 = lane & 15;
    const int g = lane >> 4;
    const int row0 = blockIdx.x * 32;
    const int col0 = blockIdx.y * 256 + w * 64;

    f32x4 acc[2][4] = {};

    const float* xr0 = x + (size_t)(row0 + r16) * C_;
    const float* xr1 = x + (size_t)(row0 + 16 + r16) * C_;

    for (int kt = 0; kt < 16; ++kt) {
        const int k0 = kt * 32 + 8 * g;
        f16x8 aHi0, aLo0, aHi1, aLo1;
        {
            float4 a0 = *(const float4*)&xr0[k0];
            float4 a1 = *(const float4*)&xr0[k0 + 4];
            cvt_split(a0, a1, aHi0, aLo0);
            float4 b0 = *(const float4*)&xr1[k0];
            float4 b1 = *(const float4*)&xr1[k0 + 4];
            cvt_split(b0, b1, aHi1, aLo1);
        }
#pragma unroll
        for (int ct = 0; ct < 4; ++ct) {
            const int c = col0 + ct * 16 + r16;
            f16x8 bHi = *(const f16x8*)&wt_hi[(size_t)c * C_ + k0];
            f16x8 bLo = *(const f16x8*)&wt_lo[(size_t)c * C_ + k0];
            acc[0][ct] = __builtin_amdgcn_mfma_f32_16x16x32_f16(aHi0, bHi, acc[0][ct], 0, 0, 0);
            acc[0][ct] = __builtin_amdgcn_mfma_f32_16x16x32_f16(aHi0, bLo, acc[0][ct], 0, 0, 0);
            acc[0][ct] = __builtin_amdgcn_mfma_f32_16x16x32_f16(aLo0, bHi, acc[0][ct], 0, 0, 0);
            acc[1][ct] = __builtin_amdgcn_mfma_f32_16x16x32_f16(aHi1, bHi, acc[1][ct], 0, 0, 0);
            acc[1][ct] = __builtin_amdgcn_mfma_f32_16x16x32_f16(aHi1, bLo, acc[1][ct], 0, 0, 0);
            acc[1][ct] = __builtin_amdgcn_mfma_f32_16x16x32_f16(aLo1, bHi, acc[1][ct], 0, 0, 0);
        }
    }

#pragma unroll
    for (int rt = 0; rt < 2; ++rt)
#pragma unroll
        for (int ct = 0; ct < 4; ++ct) {
            const int c = col0 + ct * 16 + r16;
            const float bias = bqkv[c];
#pragma unroll
            for (int j = 0; j < 4; ++j) {
                const int r = row0 + rt * 16 + 4 * g + j;
                qkv[(size_t)r * (3 * C_) + c] = acc[rt][ct][j] + bias;
            }
        }
}

// ---------------------------------------------------------------------------
// Kernel 2: attn_scores (unchanged — validated round 2)
// ---------------------------------------------------------------------------
__global__ __launch_bounds__(256) void attn_scores(const float* __restrict__ qkv,
                                                   const float* __restrict__ ow_in,
                                                   float* __restrict__ attn) {
    __shared__ float smax[4][16];
    __shared__ float ssum[4][16];

    const int tid = threadIdx.x;
    const int lane = tid & 63;
    const int w = tid >> 6;           // wave 0..3 -> key cols [w*256, w*256+256)
    const int r16 = lane & 15;        // A row / B col / D col
    const int g = lane >> 4;          // k-group: k = 8g..8g+7 (+32 for kstep1)
    const int n0 = blockIdx.x * 16;   // query-row tile
    const int bh = blockIdx.y;
    const int b = bh >> 3, h = bh & 7;
    const size_t RS = 3 * C_;

    float w0 = ow_in[0], w1 = ow_in[1], w2 = ow_in[2];
    float wm = fmaxf(w0, fmaxf(w1, w2));
    float e0 = __expf(w0 - wm), e1 = __expf(w1 - wm), e2 = __expf(w2 - wm);
    float einv = 1.0f / (e0 + e1 + e2);
    float ow0 = e0 * einv, ow1 = e1 * einv, ow2 = e2 * einv;

    const float* qrow = qkv + (size_t)(b * N_ + n0 + r16) * RS + h * HD_;
    f16x8 aHi0, aLo0, aHi1, aLo1;
    {
        float4 qa = ((const float4*)qrow)[2 * g + 0];
        float4 qb = ((const float4*)qrow)[2 * g + 1];
        float4 qc = ((const float4*)qrow)[8 + 2 * g];
        float4 qd = ((const float4*)qrow)[9 + 2 * g];
        cvt_split(qa, qb, aHi0, aLo0);
        cvt_split(qc, qd, aHi1, aLo1);
    }

    float p[16][4];

    const float* kbase = qkv + (size_t)(b * N_) * RS + C_ + h * HD_;
#pragma unroll
    for (int t = 0; t < 16; ++t) {
        const int ct = w * 16 + t;
        const float* krow = kbase + (size_t)(ct * 16 + r16) * RS;
        float4 ka = ((const float4*)krow)[2 * g + 0];
        float4 kb = ((const float4*)krow)[2 * g + 1];
        float4 kc = ((const float4*)krow)[8 + 2 * g];
        float4 kd = ((const float4*)krow)[9 + 2 * g];
        f16x8 bHi0, bLo0, bHi1, bLo1;
        cvt_split(ka, kb, bHi0, bLo0);
        cvt_split(kc, kd, bHi1, bLo1);

        f32x4 acc = {0.f, 0.f, 0.f, 0.f};
        acc = __builtin_amdgcn_mfma_f32_16x16x32_f16(aHi0, bHi0, acc, 0, 0, 0);
        acc = __builtin_amdgcn_mfma_f32_16x16x32_f16(aHi0, bLo0, acc, 0, 0, 0);
        acc = __builtin_amdgcn_mfma_f32_16x16x32_f16(aLo0, bHi0, acc, 0, 0, 0);
        acc = __builtin_amdgcn_mfma_f32_16x16x32_f16(aHi1, bHi1, acc, 0, 0, 0);
        acc = __builtin_amdgcn_mfma_f32_16x16x32_f16(aHi1, bLo1, acc, 0, 0, 0);
        acc = __builtin_amdgcn_mfma_f32_16x16x32_f16(aLo1, bHi1, acc, 0, 0, 0);

#pragma unroll
        for (int j = 0; j < 4; ++j) {
            float s = acc[j] * SCALE_;
            p[t][j] = s * (ow0 + s * (ow1 + s * ow2));
        }
    }

    float rmax[4] = {-1e30f, -1e30f, -1e30f, -1e30f};
#pragma unroll
    for (int t = 0; t < 16; ++t)
#pragma unroll
        for (int j = 0; j < 4; ++j) rmax[j] = fmaxf(rmax[j], p[t][j]);
#pragma unroll
    for (int j = 0; j < 4; ++j)
#pragma unroll
        for (int m = 1; m < 16; m <<= 1)
            rmax[j] = fmaxf(rmax[j], __shfl_xor(rmax[j], m, 64));
    if (r16 == 0) {
#pragma unroll
        for (int j = 0; j < 4; ++j) smax[w][g * 4 + j] = rmax[j];
    }
    __syncthreads();
    float gm[4];
#pragma unroll
    for (int j = 0; j < 4; ++j) {
        int rr = g * 4 + j;
        gm[j] = fmaxf(fmaxf(smax[0][rr], smax[1][rr]),
                      fmaxf(smax[2][rr], smax[3][rr]));
    }

    float rsum[4] = {0.f, 0.f, 0.f, 0.f};
#pragma unroll
    for (int t = 0; t < 16; ++t)
#pragma unroll
        for (int j = 0; j < 4; ++j) {
            float e = __expf(p[t][j] - gm[j]);
            p[t][j] = e;
            rsum[j] += e;
        }
#pragma unroll
    for (int j = 0; j < 4; ++j)
#pragma unroll
        for (int m = 1; m < 16; m <<= 1)
            rsum[j] += __shfl_xor(rsum[j], m, 64);
    if (r16 == 0) {
#pragma unroll
        for (int j = 0; j < 4; ++j) ssum[w][g * 4 + j] = rsum[j];
    }
    __syncthreads();
    float inv[4];
#pragma unroll
    for (int j = 0; j < 4; ++j) {
        int rr = g * 4 + j;
        inv[j] = 1.0f / (ssum[0][rr] + ssum[1][rr] + ssum[2][rr] + ssum[3][rr]);
    }

    float* abase = attn + ((size_t)bh * N_ + n0 + 4 * g) * N_ + w * 256 + r16;
#pragma unroll
    for (int j = 0; j < 4; ++j) {
        float* arow = abase + (size_t)j * N_;
        float sc = inv[j];
#pragma unroll
        for (int t = 0; t < 16; ++t)
            arow[t * 16] = p[t][j] * sc;
    }
}

// ---------------------------------------------------------------------------
// Kernel 3: pv_mfma — ctx[:, h*HD+d] = P @ V via f16-split MFMA.
//   Block: 64 P-rows x HD=64, 4 waves (16 rows each, 4 col-tiles).
//   A = P rows (fp32, split on the fly); B = pre-split Vt (m-contiguous f16x8).
//   No LDS, no barriers in the main loop.
// ---------------------------------------------------------------------------
__global__ __launch_bounds__(256) void pv_mfma(const float* __restrict__ attn,
                                               const _Float16* __restrict__ vt_hi,
                                               const _Float16* __restrict__ vt_lo,
                                               float* __restrict__ ctx) {
    const int tid = threadIdx.x;
    const int lane = tid & 63;
    const int w = tid >> 6;
    const int r16 = lane & 15;
    const int g = lane >> 4;
    const int n0 = blockIdx.x * 64;
    const int bh = blockIdx.y;
    const int b = bh >> 3, h = bh & 7;

    const float* prow = attn + ((size_t)bh * N_ + n0 + w * 16 + r16) * N_;
    const _Float16* vh = vt_hi + (size_t)bh * HD_ * N_;
    const _Float16* vl = vt_lo + (size_t)bh * HD_ * N_;

    f32x4 acc[4] = {};

    for (int kt = 0; kt < 32; ++kt) {
        const int k0 = kt * 32 + 8 * g;
        float4 a0 = *(const float4*)&prow[k0];
        float4 a1 = *(const float4*)&prow[k0 + 4];
        f16x8 aHi, aLo;
        cvt_split(a0, a1, aHi, aLo);
#pragma unroll
        for (int ct = 0; ct < 4; ++ct) {
            const int d = ct * 16 + r16;
            f16x8 bHi = *(const f16x8*)&vh[(size_t)d * N_ + k0];
            f16x8 bLo = *(const f16x8*)&vl[(size_t)d * N_ + k0];
            acc[ct] = __builtin_amdgcn_mfma_f32_16x16x32_f16(aHi, bHi, acc[ct], 0, 0, 0);
            acc[ct] = __builtin_amdgcn_mfma_f32_16x16x32_f16(aHi, bLo, acc[ct], 0, 0, 0);
            acc[ct] = __builtin_amdgcn_mfma_f32_16x16x32_f16(aLo, bHi, acc[ct], 0, 0, 0);
        }
    }

#pragma unroll
    for (int ct = 0; ct < 4; ++ct) {
        const int c = h * HD_ + ct * 16 + r16;
#pragma unroll
        for (int j = 0; j < 4; ++j) {
            const int r = n0 + w * 16 + 4 * g + j;
            ctx[(size_t)(b * N_ + r) * C_ + c] = acc[ct][j];
        }
    }
}

// ---------------------------------------------------------------------------
// Kernel 4: proj_gemm — y_pre = ctx @ Wproj + bproj + x  (unchanged)
// ---------------------------------------------------------------------------
__global__ __launch_bounds__(256) void proj_gemm(const float* __restrict__ ctx,
                                                 const float* __restrict__ x,
                                                 const float* __restrict__ Wproj,
                                                 const float* __restrict__ bproj,
                                                 float* __restrict__ y) {
    const int K = C_;
    const int NN = C_;
    __shared__ float As[64][17];
    __shared__ float Bs[16][64];

    const int tid = threadIdx.x;
    const int tx = tid & 15;
    const int ty = tid >> 4;
    const int row0 = blockIdx.y * 64;
    const int col0 = blockIdx.x * 64;

    float acc[4][4] = {};

    for (int kt = 0; kt < K; kt += 16) {
        {
            int lin = tid * 4;
            int m = lin >> 4;
            int k = lin & 15;
            float4 a = *(const float4*)&ctx[(size_t)(row0 + m) * K + kt + k];
            As[m][k + 0] = a.x; As[m][k + 1] = a.y;
            As[m][k + 2] = a.z; As[m][k + 3] = a.w;
        }
        {
            int lin = tid * 4;
            int kk = lin >> 6;
            int n = lin & 63;
            *(float4*)&Bs[kk][n] =
                *(const float4*)&Wproj[(size_t)(kt + kk) * NN + col0 + n];
        }
        __syncthreads();
#pragma unroll
        for (int kk = 0; kk < 16; ++kk) {
            float a[4], bb[4];
#pragma unroll
            for (int i = 0; i < 4; ++i) a[i] = As[ty * 4 + i][kk];
#pragma unroll
            for (int j = 0; j < 4; ++j) bb[j] = Bs[kk][tx * 4 + j];
#pragma unroll
            for (int i = 0; i < 4; ++i)
#pragma unroll
                for (int j = 0; j < 4; ++j) acc[i][j] += a[i] * bb[j];
        }
        __syncthreads();
    }
#pragma unroll
    for (int i = 0; i < 4; ++i) {
        int r = row0 + ty * 4 + i;
        int c = col0 + tx * 4;
        float4 xr = *(const float4*)&x[(size_t)r * C_ + c];
        float4 o;
        o.x = acc[i][0] + bproj[c + 0] + xr.x;
        o.y = acc[i][1] + bproj[c + 1] + xr.y;
        o.z = acc[i][2] + bproj[c + 2] + xr.z;
        o.w = acc[i][3] + bproj[c + 3] + xr.w;
        *(float4*)&y[(size_t)r * C_ + c] = o;
    }
}

// ---------------------------------------------------------------------------
// Kernel 5: ln_kernel (unchanged)
// ---------------------------------------------------------------------------
__global__ __launch_bounds__(256) void ln_kernel(float* __restrict__ y,
                                                 const float* __restrict__ gamma,
                                                 const float* __restrict__ beta) {
    __shared__ float wsum[4], wsq[4];
    const int row = blockIdx.x;
    const int tid = threadIdx.x;
    const int lane = tid & 63;
    const int w = tid >> 6;

    float2 v = ((const float2*)(y + (size_t)row * C_))[tid];
    float s = v.x + v.y;
    float sq = v.x * v.x + v.y * v.y;
#pragma unroll
    for (int m = 1; m < 64; m <<= 1) {
        s += __shfl_xor(s, m, 64);
        sq += __shfl_xor(sq, m, 64);
    }
    if (lane == 0) { wsum[w] = s; wsq[w] = sq; }
    __syncthreads();
    float ts = wsum[0] + wsum[1] + wsum[2] + wsum[3];
    float tq = wsq[0] + wsq[1] + wsq[2] + wsq[3];
    float mu = ts * (1.0f / C_);
    float var = tq * (1.0f / C_) - mu * mu;
    float rstd = rsqrtf(var + LN_EPS_);

    float2 g = ((const float2*)gamma)[tid];
    float2 be = ((const float2*)beta)[tid];
    float2 o;
    o.x = (v.x - mu) * rstd * g.x + be.x;
    o.y = (v.y - mu) * rstd * g.y + be.y;
    ((float2*)(y + (size_t)row * C_))[tid] = o;
}

extern "C" void kernel_launch(void* const* d_in, const int* in_sizes, int n_in,
                              void* d_out, int out_size, void* d_ws, size_t ws_size,
                              hipStream_t stream) {
    const float* x     = (const float*)d_in[0];
    const float* Wqkv  = (const float*)d_in[1];
    const float* bqkv  = (const float*)d_in[2];
    const float* ow    = (const float*)d_in[3];
    const float* Wproj = (const float*)d_in[4];
    const float* bproj = (const float*)d_in[5];
    const float* gamma = (const float*)d_in[6];
    const float* beta  = (const float*)d_in[7];

    float* out  = (float*)d_out;
    float* y    = out;                                  // [B,N,C]
    float* attn = out + (size_t)B_ * N_ * C_;           // [B,H,N,N]
    float* qkv  = (float*)d_ws;                         // [B*N, 3C]  25 MB
    float* ctx  = qkv + (size_t)B_ * N_ * 3 * C_;       // [B*N, C]    8 MB

    // Wt_hi/Wt_lo overlay the attn output region (3 MB of 128 MB); consumed by
    // qkv_gemm_mfma, then rewritten by attn_scores.
    _Float16* wt_hi = (_Float16*)attn;
    _Float16* wt_lo = wt_hi + (size_t)(3 * C_) * C_;
    // Vt_hi/Vt_lo overlay the y region (8 MB exactly); consumed by pv_mfma,
    // then rewritten by proj_gemm.
    _Float16* vt_hi = (_Float16*)y;
    _Float16* vt_lo = vt_hi + (size_t)B_ * H_ * HD_ * N_;

    dim3 g0(3 * C_ / 64, C_ / 64);                      // (24, 8)
    wsplit_qkv<<<g0, 256, 0, stream>>>(Wqkv, wt_hi, wt_lo);

    dim3 g1(B_ * N_ / 32, 3 * C_ / 256);                // (128, 6)
    qkv_gemm_mfma<<<g1, 256, 0, stream>>>(x, wt_hi, wt_lo, bqkv, qkv);

    dim3 gv(N_ / 64, B_ * H_);                          // (16, 32)
    vsplit_v<<<gv, 256, 0, stream>>>(qkv, vt_hi, vt_lo);

    dim3 g2(N_ / 16, B_ * H_);                          // (64, 32)
    attn_scores<<<g2, 256, 0, stream>>>(qkv, ow, attn);

    dim3 g3(N_ / 64, B_ * H_);                          // (16, 32)
    pv_mfma<<<g3, 256, 0, stream>>>(attn, vt_hi, vt_lo, ctx);

    dim3 g4(C_ / 64, B_ * N_ / 64);                     // (8, 64)
    proj_gemm<<<g4, 256, 0, stream>>>(ctx, x, Wproj, bproj, y);

    ln_kernel<<<B_ * N_, 256, 0, stream>>>(y, gamma, beta);
}

// Round 6
// 407.071 us; speedup vs baseline: 1.0379x; 1.0379x over previous
//
#include <hip/hip_runtime.h>
#include <math.h>

#define B_ 4
#define N_ 1024
#define C_ 512
#define H_ 8
#define HD_ 64
#define SCALE_ 0.125f
#define LN_EPS_ 1e-5f

typedef _Float16 f16x8 __attribute__((ext_vector_type(8)));
typedef float f32x4 __attribute__((ext_vector_type(4)));

// Split 8 fp32 (two float4) into f16 hi + f16 lo such that hi+lo ~= x (22-bit).
__device__ __forceinline__ void cvt_split(const float4& A, const float4& Bv,
                                          f16x8& hi, f16x8& lo) {
    float v[8] = {A.x, A.y, A.z, A.w, Bv.x, Bv.y, Bv.z, Bv.w};
#pragma unroll
    for (int i = 0; i < 8; ++i) {
        _Float16 h = (_Float16)v[i];
        hi[i] = h;
        lo[i] = (_Float16)(v[i] - (float)h);
    }
}

// ---------------------------------------------------------------------------
// Kernel 0: wsplit_qkv — transpose + f16-split Wqkv [512][1536] into
//   Wt_hi/Wt_lo [1536][512] (row = output column, k contiguous).
//   Output lives in the attn region (rewritten later by attn_scores).
// ---------------------------------------------------------------------------
__global__ __launch_bounds__(256) void wsplit_qkv(const float* __restrict__ W,
                                                  _Float16* __restrict__ wt_hi,
                                                  _Float16* __restrict__ wt_lo) {
    __shared__ float tile[64][65];
    const int tid = threadIdx.x;
    const int n0 = blockIdx.x * 64;   // col of W  (row of Wt)
    const int k0 = blockIdx.y * 64;   // row of W  (col of Wt)
#pragma unroll
    for (int i = 0; i < 16; ++i) {
        int e = tid + i * 256;
        int kk = e >> 6, nn = e & 63;
        tile[kk][nn] = W[(size_t)(k0 + kk) * (3 * C_) + n0 + nn];
    }
    __syncthreads();
#pragma unroll
    for (int i = 0; i < 16; ++i) {
        int e = tid + i * 256;
        int n = e >> 6, k = e & 63;
        float v = tile[k][n];
        _Float16 h = (_Float16)v;
        wt_hi[(size_t)(n0 + n) * C_ + k0 + k] = h;
        wt_lo[(size_t)(n0 + n) * C_ + k0 + k] = (_Float16)(v - (float)h);
    }
}

// ---------------------------------------------------------------------------
// Kernel 0b: vsplit_v — transpose + f16-split V (from qkv) into
//   Vt_hi/Vt_lo [B*H][HD][N] (m contiguous). Lives in the y region of out
//   (8 MB exactly), which proj_gemm rewrites after pv_mfma consumes it.
// ---------------------------------------------------------------------------
__global__ __launch_bounds__(256) void vsplit_v(const float* __restrict__ qkv,
                                                _Float16* __restrict__ vt_hi,
                                                _Float16* __restrict__ vt_lo) {
    __shared__ float tile[64][65];
    const int tid = threadIdx.x;
    const int m0 = blockIdx.x * 64;
    const int bh = blockIdx.y;
    const int b = bh >> 3, h = bh & 7;
    const size_t RS = 3 * C_;
#pragma unroll
    for (int i = 0; i < 16; ++i) {
        int e = tid + i * 256;
        int mm = e >> 6, d = e & 63;
        tile[mm][d] = qkv[(size_t)(b * N_ + m0 + mm) * RS + 2 * C_ + h * HD_ + d];
    }
    __syncthreads();
#pragma unroll
    for (int i = 0; i < 16; ++i) {
        int e = tid + i * 256;
        int d = e >> 6, mm = e & 63;
        float v = tile[mm][d];
        _Float16 hh = (_Float16)v;
        size_t idx = ((size_t)bh * HD_ + d) * N_ + m0 + mm;
        vt_hi[idx] = hh;
        vt_lo[idx] = (_Float16)(v - (float)hh);
    }
}

// ---------------------------------------------------------------------------
// Kernel 1: qkv_gemm_mfma (unchanged — validated round 3)
// ---------------------------------------------------------------------------
__global__ __launch_bounds__(256) void qkv_gemm_mfma(const float* __restrict__ x,
                                                     const _Float16* __restrict__ wt_hi,
                                                     const _Float16* __restrict__ wt_lo,
                                                     const float* __restrict__ bqkv,
                                                     float* __restrict__ qkv) {
    const int tid = threadIdx.x;
    const int lane = tid & 63;
    const int w = tid >> 6;
    const int r16 = lane & 15;
    const int g = lane >> 4;
    const int row0 = blockIdx.x * 32;
    const int col0 = blockIdx.y * 256 + w * 64;

    f32x4 acc[2][4] = {};

    const float* xr0 = x + (size_t)(row0 + r16) * C_;
    const float* xr1 = x + (size_t)(row0 + 16 + r16) * C_;

    for (int kt = 0; kt < 16; ++kt) {
        const int k0 = kt * 32 + 8 * g;
        f16x8 aHi0, aLo0, aHi1, aLo1;
        {
            float4 a0 = *(const float4*)&xr0[k0];
            float4 a1 = *(const float4*)&xr0[k0 + 4];
            cvt_split(a0, a1, aHi0, aLo0);
            float4 b0 = *(const float4*)&xr1[k0];
            float4 b1 = *(const float4*)&xr1[k0 + 4];
            cvt_split(b0, b1, aHi1, aLo1);
        }
#pragma unroll
        for (int ct = 0; ct < 4; ++ct) {
            const int c = col0 + ct * 16 + r16;
            f16x8 bHi = *(const f16x8*)&wt_hi[(size_t)c * C_ + k0];
            f16x8 bLo = *(const f16x8*)&wt_lo[(size_t)c * C_ + k0];
            acc[0][ct] = __builtin_amdgcn_mfma_f32_16x16x32_f16(aHi0, bHi, acc[0][ct], 0, 0, 0);
            acc[0][ct] = __builtin_amdgcn_mfma_f32_16x16x32_f16(aHi0, bLo, acc[0][ct], 0, 0, 0);
            acc[0][ct] = __builtin_amdgcn_mfma_f32_16x16x32_f16(aLo0, bHi, acc[0][ct], 0, 0, 0);
            acc[1][ct] = __builtin_amdgcn_mfma_f32_16x16x32_f16(aHi1, bHi, acc[1][ct], 0, 0, 0);
            acc[1][ct] = __builtin_amdgcn_mfma_f32_16x16x32_f16(aHi1, bLo, acc[1][ct], 0, 0, 0);
            acc[1][ct] = __builtin_amdgcn_mfma_f32_16x16x32_f16(aLo1, bHi, acc[1][ct], 0, 0, 0);
        }
    }

#pragma unroll
    for (int rt = 0; rt < 2; ++rt)
#pragma unroll
        for (int ct = 0; ct < 4; ++ct) {
            const int c = col0 + ct * 16 + r16;
            const float bias = bqkv[c];
#pragma unroll
            for (int j = 0; j < 4; ++j) {
                const int r = row0 + rt * 16 + 4 * g + j;
                qkv[(size_t)r * (3 * C_) + c] = acc[rt][ct][j] + bias;
            }
        }
}

// ---------------------------------------------------------------------------
// Kernel 2: attn_scores (unchanged — validated round 2)
// ---------------------------------------------------------------------------
__global__ __launch_bounds__(256) void attn_scores(const float* __restrict__ qkv,
                                                   const float* __restrict__ ow_in,
                                                   float* __restrict__ attn) {
    __shared__ float smax[4][16];
    __shared__ float ssum[4][16];

    const int tid = threadIdx.x;
    const int lane = tid & 63;
    const int w = tid >> 6;           // wave 0..3 -> key cols [w*256, w*256+256)
    const int r16 = lane & 15;        // A row / B col / D col
    const int g = lane >> 4;          // k-group: k = 8g..8g+7 (+32 for kstep1)
    const int n0 = blockIdx.x * 16;   // query-row tile
    const int bh = blockIdx.y;
    const int b = bh >> 3, h = bh & 7;
    const size_t RS = 3 * C_;

    float w0 = ow_in[0], w1 = ow_in[1], w2 = ow_in[2];
    float wm = fmaxf(w0, fmaxf(w1, w2));
    float e0 = __expf(w0 - wm), e1 = __expf(w1 - wm), e2 = __expf(w2 - wm);
    float einv = 1.0f / (e0 + e1 + e2);
    float ow0 = e0 * einv, ow1 = e1 * einv, ow2 = e2 * einv;

    const float* qrow = qkv + (size_t)(b * N_ + n0 + r16) * RS + h * HD_;
    f16x8 aHi0, aLo0, aHi1, aLo1;
    {
        float4 qa = ((const float4*)qrow)[2 * g + 0];
        float4 qb = ((const float4*)qrow)[2 * g + 1];
        float4 qc = ((const float4*)qrow)[8 + 2 * g];
        float4 qd = ((const float4*)qrow)[9 + 2 * g];
        cvt_split(qa, qb, aHi0, aLo0);
        cvt_split(qc, qd, aHi1, aLo1);
    }

    float p[16][4];

    const float* kbase = qkv + (size_t)(b * N_) * RS + C_ + h * HD_;
#pragma unroll
    for (int t = 0; t < 16; ++t) {
        const int ct = w * 16 + t;
        const float* krow = kbase + (size_t)(ct * 16 + r16) * RS;
        float4 ka = ((const float4*)krow)[2 * g + 0];
        float4 kb = ((const float4*)krow)[2 * g + 1];
        float4 kc = ((const float4*)krow)[8 + 2 * g];
        float4 kd = ((const float4*)krow)[9 + 2 * g];
        f16x8 bHi0, bLo0, bHi1, bLo1;
        cvt_split(ka, kb, bHi0, bLo0);
        cvt_split(kc, kd, bHi1, bLo1);

        f32x4 acc = {0.f, 0.f, 0.f, 0.f};
        acc = __builtin_amdgcn_mfma_f32_16x16x32_f16(aHi0, bHi0, acc, 0, 0, 0);
        acc = __builtin_amdgcn_mfma_f32_16x16x32_f16(aHi0, bLo0, acc, 0, 0, 0);
        acc = __builtin_amdgcn_mfma_f32_16x16x32_f16(aLo0, bHi0, acc, 0, 0, 0);
        acc = __builtin_amdgcn_mfma_f32_16x16x32_f16(aHi1, bHi1, acc, 0, 0, 0);
        acc = __builtin_amdgcn_mfma_f32_16x16x32_f16(aHi1, bLo1, acc, 0, 0, 0);
        acc = __builtin_amdgcn_mfma_f32_16x16x32_f16(aLo1, bHi1, acc, 0, 0, 0);

#pragma unroll
        for (int j = 0; j < 4; ++j) {
            float s = acc[j] * SCALE_;
            p[t][j] = s * (ow0 + s * (ow1 + s * ow2));
        }
    }

    float rmax[4] = {-1e30f, -1e30f, -1e30f, -1e30f};
#pragma unroll
    for (int t = 0; t < 16; ++t)
#pragma unroll
        for (int j = 0; j < 4; ++j) rmax[j] = fmaxf(rmax[j], p[t][j]);
#pragma unroll
    for (int j = 0; j < 4; ++j)
#pragma unroll
        for (int m = 1; m < 16; m <<= 1)
            rmax[j] = fmaxf(rmax[j], __shfl_xor(rmax[j], m, 64));
    if (r16 == 0) {
#pragma unroll
        for (int j = 0; j < 4; ++j) smax[w][g * 4 + j] = rmax[j];
    }
    __syncthreads();
    float gm[4];
#pragma unroll
    for (int j = 0; j < 4; ++j) {
        int rr = g * 4 + j;
        gm[j] = fmaxf(fmaxf(smax[0][rr], smax[1][rr]),
                      fmaxf(smax[2][rr], smax[3][rr]));
    }

    float rsum[4] = {0.f, 0.f, 0.f, 0.f};
#pragma unroll
    for (int t = 0; t < 16; ++t)
#pragma unroll
        for (int j = 0; j < 4; ++j) {
            float e = __expf(p[t][j] - gm[j]);
            p[t][j] = e;
            rsum[j] += e;
        }
#pragma unroll
    for (int j = 0; j < 4; ++j)
#pragma unroll
        for (int m = 1; m < 16; m <<= 1)
            rsum[j] += __shfl_xor(rsum[j], m, 64);
    if (r16 == 0) {
#pragma unroll
        for (int j = 0; j < 4; ++j) ssum[w][g * 4 + j] = rsum[j];
    }
    __syncthreads();
    float inv[4];
#pragma unroll
    for (int j = 0; j < 4; ++j) {
        int rr = g * 4 + j;
        inv[j] = 1.0f / (ssum[0][rr] + ssum[1][rr] + ssum[2][rr] + ssum[3][rr]);
    }

    float* abase = attn + ((size_t)bh * N_ + n0 + 4 * g) * N_ + w * 256 + r16;
#pragma unroll
    for (int j = 0; j < 4; ++j) {
        float* arow = abase + (size_t)j * N_;
        float sc = inv[j];
#pragma unroll
        for (int t = 0; t < 16; ++t)
            arow[t * 16] = p[t][j] * sc;
    }
}

// ---------------------------------------------------------------------------
// Kernel 3: pv_mfma — ctx = P @ V via f16-split MFMA, 4-deep P prefetch.
//   Round-5 counters showed latency-bound (MfmaUtil 5%, VALU 6%, BW 15%,
//   VGPR 24 = no in-flight loads). Fix: unroll kt x4, issue all 8 P-loads
//   before any use so 8 HBM transactions overlap per wave.
// ---------------------------------------------------------------------------
__global__ __launch_bounds__(256) void pv_mfma(const float* __restrict__ attn,
                                               const _Float16* __restrict__ vt_hi,
                                               const _Float16* __restrict__ vt_lo,
                                               float* __restrict__ ctx) {
    const int tid = threadIdx.x;
    const int lane = tid & 63;
    const int w = tid >> 6;
    const int r16 = lane & 15;
    const int g = lane >> 4;
    const int n0 = blockIdx.x * 64;
    const int bh = blockIdx.y;
    const int b = bh >> 3, h = bh & 7;

    const float* prow = attn + ((size_t)bh * N_ + n0 + w * 16 + r16) * N_ + 8 * g;
    const _Float16* vh = vt_hi + (size_t)bh * HD_ * N_;
    const _Float16* vl = vt_lo + (size_t)bh * HD_ * N_;

    f32x4 acc[4] = {};

    for (int kt = 0; kt < 32; kt += 4) {
        // ---- issue all 8 P loads for 4 sub-iterations up front (MLP) ----
        float4 p0[4], p1[4];
#pragma unroll
        for (int u = 0; u < 4; ++u) {
            const int k0 = (kt + u) * 32;
            p0[u] = *(const float4*)&prow[k0];
            p1[u] = *(const float4*)&prow[k0 + 4];
        }
        // ---- compute; V loads are L2-resident, hidden under MFMAs ----
#pragma unroll
        for (int u = 0; u < 4; ++u) {
            const int k0 = (kt + u) * 32 + 8 * g;
            f16x8 aHi, aLo;
            cvt_split(p0[u], p1[u], aHi, aLo);
#pragma unroll
            for (int ct = 0; ct < 4; ++ct) {
                const int d = ct * 16 + r16;
                f16x8 bHi = *(const f16x8*)&vh[(size_t)d * N_ + k0];
                f16x8 bLo = *(const f16x8*)&vl[(size_t)d * N_ + k0];
                acc[ct] = __builtin_amdgcn_mfma_f32_16x16x32_f16(aHi, bHi, acc[ct], 0, 0, 0);
                acc[ct] = __builtin_amdgcn_mfma_f32_16x16x32_f16(aHi, bLo, acc[ct], 0, 0, 0);
                acc[ct] = __builtin_amdgcn_mfma_f32_16x16x32_f16(aLo, bHi, acc[ct], 0, 0, 0);
            }
        }
    }

#pragma unroll
    for (int ct = 0; ct < 4; ++ct) {
        const int c = h * HD_ + ct * 16 + r16;
#pragma unroll
        for (int j = 0; j < 4; ++j) {
            const int r = n0 + w * 16 + 4 * g + j;
            ctx[(size_t)(b * N_ + r) * C_ + c] = acc[ct][j];
        }
    }
}

// ---------------------------------------------------------------------------
// Kernel 4: proj_gemm — y_pre = ctx @ Wproj + bproj + x  (unchanged)
// ---------------------------------------------------------------------------
__global__ __launch_bounds__(256) void proj_gemm(const float* __restrict__ ctx,
                                                 const float* __restrict__ x,
                                                 const float* __restrict__ Wproj,
                                                 const float* __restrict__ bproj,
                                                 float* __restrict__ y) {
    const int K = C_;
    const int NN = C_;
    __shared__ float As[64][17];
    __shared__ float Bs[16][64];

    const int tid = threadIdx.x;
    const int tx = tid & 15;
    const int ty = tid >> 4;
    const int row0 = blockIdx.y * 64;
    const int col0 = blockIdx.x * 64;

    float acc[4][4] = {};

    for (int kt = 0; kt < K; kt += 16) {
        {
            int lin = tid * 4;
            int m = lin >> 4;
            int k = lin & 15;
            float4 a = *(const float4*)&ctx[(size_t)(row0 + m) * K + kt + k];
            As[m][k + 0] = a.x; As[m][k + 1] = a.y;
            As[m][k + 2] = a.z; As[m][k + 3] = a.w;
        }
        {
            int lin = tid * 4;
            int kk = lin >> 6;
            int n = lin & 63;
            *(float4*)&Bs[kk][n] =
                *(const float4*)&Wproj[(size_t)(kt + kk) * NN + col0 + n];
        }
        __syncthreads();
#pragma unroll
        for (int kk = 0; kk < 16; ++kk) {
            float a[4], bb[4];
#pragma unroll
            for (int i = 0; i < 4; ++i) a[i] = As[ty * 4 + i][kk];
#pragma unroll
            for (int j = 0; j < 4; ++j) bb[j] = Bs[kk][tx * 4 + j];
#pragma unroll
            for (int i = 0; i < 4; ++i)
#pragma unroll
                for (int j = 0; j < 4; ++j) acc[i][j] += a[i] * bb[j];
        }
        __syncthreads();
    }
#pragma unroll
    for (int i = 0; i < 4; ++i) {
        int r = row0 + ty * 4 + i;
        int c = col0 + tx * 4;
        float4 xr = *(const float4*)&x[(size_t)r * C_ + c];
        float4 o;
        o.x = acc[i][0] + bproj[c + 0] + xr.x;
        o.y = acc[i][1] + bproj[c + 1] + xr.y;
        o.z = acc[i][2] + bproj[c + 2] + xr.z;
        o.w = acc[i][3] + bproj[c + 3] + xr.w;
        *(float4*)&y[(size_t)r * C_ + c] = o;
    }
}

// ---------------------------------------------------------------------------
// Kernel 5: ln_kernel (unchanged)
// ---------------------------------------------------------------------------
__global__ __launch_bounds__(256) void ln_kernel(float* __restrict__ y,
                                                 const float* __restrict__ gamma,
                                                 const float* __restrict__ beta) {
    __shared__ float wsum[4], wsq[4];
    const int row = blockIdx.x;
    const int tid = threadIdx.x;
    const int lane = tid & 63;
    const int w = tid >> 6;

    float2 v = ((const float2*)(y + (size_t)row * C_))[tid];
    float s = v.x + v.y;
    float sq = v.x * v.x + v.y * v.y;
#pragma unroll
    for (int m = 1; m < 64; m <<= 1) {
        s += __shfl_xor(s, m, 64);
        sq += __shfl_xor(sq, m, 64);
    }
    if (lane == 0) { wsum[w] = s; wsq[w] = sq; }
    __syncthreads();
    float ts = wsum[0] + wsum[1] + wsum[2] + wsum[3];
    float tq = wsq[0] + wsq[1] + wsq[2] + wsq[3];
    float mu = ts * (1.0f / C_);
    float var = tq * (1.0f / C_) - mu * mu;
    float rstd = rsqrtf(var + LN_EPS_);

    float2 g = ((const float2*)gamma)[tid];
    float2 be = ((const float2*)beta)[tid];
    float2 o;
    o.x = (v.x - mu) * rstd * g.x + be.x;
    o.y = (v.y - mu) * rstd * g.y + be.y;
    ((float2*)(y + (size_t)row * C_))[tid] = o;
}

extern "C" void kernel_launch(void* const* d_in, const int* in_sizes, int n_in,
                              void* d_out, int out_size, void* d_ws, size_t ws_size,
                              hipStream_t stream) {
    const float* x     = (const float*)d_in[0];
    const float* Wqkv  = (const float*)d_in[1];
    const float* bqkv  = (const float*)d_in[2];
    const float* ow    = (const float*)d_in[3];
    const float* Wproj = (const float*)d_in[4];
    const float* bproj = (const float*)d_in[5];
    const float* gamma = (const float*)d_in[6];
    const float* beta  = (const float*)d_in[7];

    float* out  = (float*)d_out;
    float* y    = out;                                  // [B,N,C]
    float* attn = out + (size_t)B_ * N_ * C_;           // [B,H,N,N]
    float* qkv  = (float*)d_ws;                         // [B*N, 3C]  25 MB
    float* ctx  = qkv + (size_t)B_ * N_ * 3 * C_;       // [B*N, C]    8 MB

    // Wt_hi/Wt_lo overlay the attn output region (3 MB of 128 MB); consumed by
    // qkv_gemm_mfma, then rewritten by attn_scores.
    _Float16* wt_hi = (_Float16*)attn;
    _Float16* wt_lo = wt_hi + (size_t)(3 * C_) * C_;
    // Vt_hi/Vt_lo overlay the y region (8 MB exactly); consumed by pv_mfma,
    // then rewritten by proj_gemm.
    _Float16* vt_hi = (_Float16*)y;
    _Float16* vt_lo = vt_hi + (size_t)B_ * H_ * HD_ * N_;

    dim3 g0(3 * C_ / 64, C_ / 64);                      // (24, 8)
    wsplit_qkv<<<g0, 256, 0, stream>>>(Wqkv, wt_hi, wt_lo);

    dim3 g1(B_ * N_ / 32, 3 * C_ / 256);                // (128, 6)
    qkv_gemm_mfma<<<g1, 256, 0, stream>>>(x, wt_hi, wt_lo, bqkv, qkv);

    dim3 gv(N_ / 64, B_ * H_);                          // (16, 32)
    vsplit_v<<<gv, 256, 0, stream>>>(qkv, vt_hi, vt_lo);

    dim3 g2(N_ / 16, B_ * H_);                          // (64, 32)
    attn_scores<<<g2, 256, 0, stream>>>(qkv, ow, attn);

    dim3 g3(N_ / 64, B_ * H_);                          // (16, 32)
    pv_mfma<<<g3, 256, 0, stream>>>(attn, vt_hi, vt_lo, ctx);

    dim3 g4(C_ / 64, B_ * N_ / 64);                     // (8, 64)
    proj_gemm<<<g4, 256, 0, stream>>>(ctx, x, Wproj, bproj, y);

    ln_kernel<<<B_ * N_, 256, 0, stream>>>(y, gamma, beta);
}

// Round 7
// 399.819 us; speedup vs baseline: 1.0567x; 1.0181x over previous
//
#include <hip/hip_runtime.h>
#include <math.h>

#define B_ 4
#define N_ 1024
#define C_ 512
#define H_ 8
#define HD_ 64
#define SCALE_ 0.125f
#define LN_EPS_ 1e-5f

typedef _Float16 f16x8 __attribute__((ext_vector_type(8)));
typedef float f32x4 __attribute__((ext_vector_type(4)));

// Split 8 fp32 (two float4) into f16 hi + f16 lo such that hi+lo ~= x (22-bit).
__device__ __forceinline__ void cvt_split(const float4& A, const float4& Bv,
                                          f16x8& hi, f16x8& lo) {
    float v[8] = {A.x, A.y, A.z, A.w, Bv.x, Bv.y, Bv.z, Bv.w};
#pragma unroll
    for (int i = 0; i < 8; ++i) {
        _Float16 h = (_Float16)v[i];
        hi[i] = h;
        lo[i] = (_Float16)(v[i] - (float)h);
    }
}

// ---------------------------------------------------------------------------
// Kernel 0: wsplit_qkv — transpose + f16-split Wqkv [512][1536] into
//   Wt_hi/Wt_lo [1536][512]. Lives in attn region (rewritten by attn_scores).
// ---------------------------------------------------------------------------
__global__ __launch_bounds__(256) void wsplit_qkv(const float* __restrict__ W,
                                                  _Float16* __restrict__ wt_hi,
                                                  _Float16* __restrict__ wt_lo) {
    __shared__ float tile[64][65];
    const int tid = threadIdx.x;
    const int n0 = blockIdx.x * 64;   // col of W  (row of Wt)
    const int k0 = blockIdx.y * 64;   // row of W  (col of Wt)
#pragma unroll
    for (int i = 0; i < 16; ++i) {
        int e = tid + i * 256;
        int kk = e >> 6, nn = e & 63;
        tile[kk][nn] = W[(size_t)(k0 + kk) * (3 * C_) + n0 + nn];
    }
    __syncthreads();
#pragma unroll
    for (int i = 0; i < 16; ++i) {
        int e = tid + i * 256;
        int n = e >> 6, k = e & 63;
        float v = tile[k][n];
        _Float16 h = (_Float16)v;
        wt_hi[(size_t)(n0 + n) * C_ + k0 + k] = h;
        wt_lo[(size_t)(n0 + n) * C_ + k0 + k] = (_Float16)(v - (float)h);
    }
}

// ---------------------------------------------------------------------------
// Kernel 0c: wsplit_proj — transpose + f16-split Wproj [512][512] into
//   wp_hi/wp_lo [512][512] (row = output col, k contiguous). Lives in ws tail.
// ---------------------------------------------------------------------------
__global__ __launch_bounds__(256) void wsplit_proj(const float* __restrict__ W,
                                                   _Float16* __restrict__ wp_hi,
                                                   _Float16* __restrict__ wp_lo) {
    __shared__ float tile[64][65];
    const int tid = threadIdx.x;
    const int n0 = blockIdx.x * 64;
    const int k0 = blockIdx.y * 64;
#pragma unroll
    for (int i = 0; i < 16; ++i) {
        int e = tid + i * 256;
        int kk = e >> 6, nn = e & 63;
        tile[kk][nn] = W[(size_t)(k0 + kk) * C_ + n0 + nn];
    }
    __syncthreads();
#pragma unroll
    for (int i = 0; i < 16; ++i) {
        int e = tid + i * 256;
        int n = e >> 6, k = e & 63;
        float v = tile[k][n];
        _Float16 h = (_Float16)v;
        wp_hi[(size_t)(n0 + n) * C_ + k0 + k] = h;
        wp_lo[(size_t)(n0 + n) * C_ + k0 + k] = (_Float16)(v - (float)h);
    }
}

// ---------------------------------------------------------------------------
// Kernel 0b: vsplit_v — transpose + f16-split V (from qkv) into
//   Vt_hi/Vt_lo [B*H][HD][N]. Lives in y region (rewritten by proj_mfma).
// ---------------------------------------------------------------------------
__global__ __launch_bounds__(256) void vsplit_v(const float* __restrict__ qkv,
                                                _Float16* __restrict__ vt_hi,
                                                _Float16* __restrict__ vt_lo) {
    __shared__ float tile[64][65];
    const int tid = threadIdx.x;
    const int m0 = blockIdx.x * 64;
    const int bh = blockIdx.y;
    const int b = bh >> 3, h = bh & 7;
    const size_t RS = 3 * C_;
#pragma unroll
    for (int i = 0; i < 16; ++i) {
        int e = tid + i * 256;
        int mm = e >> 6, d = e & 63;
        tile[mm][d] = qkv[(size_t)(b * N_ + m0 + mm) * RS + 2 * C_ + h * HD_ + d];
    }
    __syncthreads();
#pragma unroll
    for (int i = 0; i < 16; ++i) {
        int e = tid + i * 256;
        int d = e >> 6, mm = e & 63;
        float v = tile[mm][d];
        _Float16 hh = (_Float16)v;
        size_t idx = ((size_t)bh * HD_ + d) * N_ + m0 + mm;
        vt_hi[idx] = hh;
        vt_lo[idx] = (_Float16)(v - (float)hh);
    }
}

// ---------------------------------------------------------------------------
// Kernel 1: qkv_gemm_mfma (unchanged — validated round 3)
// ---------------------------------------------------------------------------
__global__ __launch_bounds__(256) void qkv_gemm_mfma(const float* __restrict__ x,
                                                     const _Float16* __restrict__ wt_hi,
                                                     const _Float16* __restrict__ wt_lo,
                                                     const float* __restrict__ bqkv,
                                                     float* __restrict__ qkv) {
    const int tid = threadIdx.x;
    const int lane = tid & 63;
    const int w = tid >> 6;
    const int r16 = lane & 15;
    const int g = lane >> 4;
    const int row0 = blockIdx.x * 32;
    const int col0 = blockIdx.y * 256 + w * 64;

    f32x4 acc[2][4] = {};

    const float* xr0 = x + (size_t)(row0 + r16) * C_;
    const float* xr1 = x + (size_t)(row0 + 16 + r16) * C_;

    for (int kt = 0; kt < 16; ++kt) {
        const int k0 = kt * 32 + 8 * g;
        f16x8 aHi0, aLo0, aHi1, aLo1;
        {
            float4 a0 = *(const float4*)&xr0[k0];
            float4 a1 = *(const float4*)&xr0[k0 + 4];
            cvt_split(a0, a1, aHi0, aLo0);
            float4 b0 = *(const float4*)&xr1[k0];
            float4 b1 = *(const float4*)&xr1[k0 + 4];
            cvt_split(b0, b1, aHi1, aLo1);
        }
#pragma unroll
        for (int ct = 0; ct < 4; ++ct) {
            const int c = col0 + ct * 16 + r16;
            f16x8 bHi = *(const f16x8*)&wt_hi[(size_t)c * C_ + k0];
            f16x8 bLo = *(const f16x8*)&wt_lo[(size_t)c * C_ + k0];
            acc[0][ct] = __builtin_amdgcn_mfma_f32_16x16x32_f16(aHi0, bHi, acc[0][ct], 0, 0, 0);
            acc[0][ct] = __builtin_amdgcn_mfma_f32_16x16x32_f16(aHi0, bLo, acc[0][ct], 0, 0, 0);
            acc[0][ct] = __builtin_amdgcn_mfma_f32_16x16x32_f16(aLo0, bHi, acc[0][ct], 0, 0, 0);
            acc[1][ct] = __builtin_amdgcn_mfma_f32_16x16x32_f16(aHi1, bHi, acc[1][ct], 0, 0, 0);
            acc[1][ct] = __builtin_amdgcn_mfma_f32_16x16x32_f16(aHi1, bLo, acc[1][ct], 0, 0, 0);
            acc[1][ct] = __builtin_amdgcn_mfma_f32_16x16x32_f16(aLo1, bHi, acc[1][ct], 0, 0, 0);
        }
    }

#pragma unroll
    for (int rt = 0; rt < 2; ++rt)
#pragma unroll
        for (int ct = 0; ct < 4; ++ct) {
            const int c = col0 + ct * 16 + r16;
            const float bias = bqkv[c];
#pragma unroll
            for (int j = 0; j < 4; ++j) {
                const int r = row0 + rt * 16 + 4 * g + j;
                qkv[(size_t)r * (3 * C_) + c] = acc[rt][ct][j] + bias;
            }
        }
}

// ---------------------------------------------------------------------------
// Kernel 2: attn_scores (unchanged — validated round 2)
// ---------------------------------------------------------------------------
__global__ __launch_bounds__(256) void attn_scores(const float* __restrict__ qkv,
                                                   const float* __restrict__ ow_in,
                                                   float* __restrict__ attn) {
    __shared__ float smax[4][16];
    __shared__ float ssum[4][16];

    const int tid = threadIdx.x;
    const int lane = tid & 63;
    const int w = tid >> 6;           // wave 0..3 -> key cols [w*256, w*256+256)
    const int r16 = lane & 15;        // A row / B col / D col
    const int g = lane >> 4;          // k-group: k = 8g..8g+7 (+32 for kstep1)
    const int n0 = blockIdx.x * 16;   // query-row tile
    const int bh = blockIdx.y;
    const int b = bh >> 3, h = bh & 7;
    const size_t RS = 3 * C_;

    float w0 = ow_in[0], w1 = ow_in[1], w2 = ow_in[2];
    float wm = fmaxf(w0, fmaxf(w1, w2));
    float e0 = __expf(w0 - wm), e1 = __expf(w1 - wm), e2 = __expf(w2 - wm);
    float einv = 1.0f / (e0 + e1 + e2);
    float ow0 = e0 * einv, ow1 = e1 * einv, ow2 = e2 * einv;

    const float* qrow = qkv + (size_t)(b * N_ + n0 + r16) * RS + h * HD_;
    f16x8 aHi0, aLo0, aHi1, aLo1;
    {
        float4 qa = ((const float4*)qrow)[2 * g + 0];
        float4 qb = ((const float4*)qrow)[2 * g + 1];
        float4 qc = ((const float4*)qrow)[8 + 2 * g];
        float4 qd = ((const float4*)qrow)[9 + 2 * g];
        cvt_split(qa, qb, aHi0, aLo0);
        cvt_split(qc, qd, aHi1, aLo1);
    }

    float p[16][4];

    const float* kbase = qkv + (size_t)(b * N_) * RS + C_ + h * HD_;
#pragma unroll
    for (int t = 0; t < 16; ++t) {
        const int ct = w * 16 + t;
        const float* krow = kbase + (size_t)(ct * 16 + r16) * RS;
        float4 ka = ((const float4*)krow)[2 * g + 0];
        float4 kb = ((const float4*)krow)[2 * g + 1];
        float4 kc = ((const float4*)krow)[8 + 2 * g];
        float4 kd = ((const float4*)krow)[9 + 2 * g];
        f16x8 bHi0, bLo0, bHi1, bLo1;
        cvt_split(ka, kb, bHi0, bLo0);
        cvt_split(kc, kd, bHi1, bLo1);

        f32x4 acc = {0.f, 0.f, 0.f, 0.f};
        acc = __builtin_amdgcn_mfma_f32_16x16x32_f16(aHi0, bHi0, acc, 0, 0, 0);
        acc = __builtin_amdgcn_mfma_f32_16x16x32_f16(aHi0, bLo0, acc, 0, 0, 0);
        acc = __builtin_amdgcn_mfma_f32_16x16x32_f16(aLo0, bHi0, acc, 0, 0, 0);
        acc = __builtin_amdgcn_mfma_f32_16x16x32_f16(aHi1, bHi1, acc, 0, 0, 0);
        acc = __builtin_amdgcn_mfma_f32_16x16x32_f16(aHi1, bLo1, acc, 0, 0, 0);
        acc = __builtin_amdgcn_mfma_f32_16x16x32_f16(aLo1, bHi1, acc, 0, 0, 0);

#pragma unroll
        for (int j = 0; j < 4; ++j) {
            float s = acc[j] * SCALE_;
            p[t][j] = s * (ow0 + s * (ow1 + s * ow2));
        }
    }

    float rmax[4] = {-1e30f, -1e30f, -1e30f, -1e30f};
#pragma unroll
    for (int t = 0; t < 16; ++t)
#pragma unroll
        for (int j = 0; j < 4; ++j) rmax[j] = fmaxf(rmax[j], p[t][j]);
#pragma unroll
    for (int j = 0; j < 4; ++j)
#pragma unroll
        for (int m = 1; m < 16; m <<= 1)
            rmax[j] = fmaxf(rmax[j], __shfl_xor(rmax[j], m, 64));
    if (r16 == 0) {
#pragma unroll
        for (int j = 0; j < 4; ++j) smax[w][g * 4 + j] = rmax[j];
    }
    __syncthreads();
    float gm[4];
#pragma unroll
    for (int j = 0; j < 4; ++j) {
        int rr = g * 4 + j;
        gm[j] = fmaxf(fmaxf(smax[0][rr], smax[1][rr]),
                      fmaxf(smax[2][rr], smax[3][rr]));
    }

    float rsum[4] = {0.f, 0.f, 0.f, 0.f};
#pragma unroll
    for (int t = 0; t < 16; ++t)
#pragma unroll
        for (int j = 0; j < 4; ++j) {
            float e = __expf(p[t][j] - gm[j]);
            p[t][j] = e;
            rsum[j] += e;
        }
#pragma unroll
    for (int j = 0; j < 4; ++j)
#pragma unroll
        for (int m = 1; m < 16; m <<= 1)
            rsum[j] += __shfl_xor(rsum[j], m, 64);
    if (r16 == 0) {
#pragma unroll
        for (int j = 0; j < 4; ++j) ssum[w][g * 4 + j] = rsum[j];
    }
    __syncthreads();
    float inv[4];
#pragma unroll
    for (int j = 0; j < 4; ++j) {
        int rr = g * 4 + j;
        inv[j] = 1.0f / (ssum[0][rr] + ssum[1][rr] + ssum[2][rr] + ssum[3][rr]);
    }

    float* abase = attn + ((size_t)bh * N_ + n0 + 4 * g) * N_ + w * 256 + r16;
#pragma unroll
    for (int j = 0; j < 4; ++j) {
        float* arow = abase + (size_t)j * N_;
        float sc = inv[j];
#pragma unroll
        for (int t = 0; t < 16; ++t)
            arow[t * 16] = p[t][j] * sc;
    }
}

// ---------------------------------------------------------------------------
// Kernel 3: pv_mfma (unchanged — validated round 6, 4-deep P prefetch)
// ---------------------------------------------------------------------------
__global__ __launch_bounds__(256) void pv_mfma(const float* __restrict__ attn,
                                               const _Float16* __restrict__ vt_hi,
                                               const _Float16* __restrict__ vt_lo,
                                               float* __restrict__ ctx) {
    const int tid = threadIdx.x;
    const int lane = tid & 63;
    const int w = tid >> 6;
    const int r16 = lane & 15;
    const int g = lane >> 4;
    const int n0 = blockIdx.x * 64;
    const int bh = blockIdx.y;
    const int b = bh >> 3, h = bh & 7;

    const float* prow = attn + ((size_t)bh * N_ + n0 + w * 16 + r16) * N_ + 8 * g;
    const _Float16* vh = vt_hi + (size_t)bh * HD_ * N_;
    const _Float16* vl = vt_lo + (size_t)bh * HD_ * N_;

    f32x4 acc[4] = {};

    for (int kt = 0; kt < 32; kt += 4) {
        float4 p0[4], p1[4];
#pragma unroll
        for (int u = 0; u < 4; ++u) {
            const int k0 = (kt + u) * 32;
            p0[u] = *(const float4*)&prow[k0];
            p1[u] = *(const float4*)&prow[k0 + 4];
        }
#pragma unroll
        for (int u = 0; u < 4; ++u) {
            const int k0 = (kt + u) * 32 + 8 * g;
            f16x8 aHi, aLo;
            cvt_split(p0[u], p1[u], aHi, aLo);
#pragma unroll
            for (int ct = 0; ct < 4; ++ct) {
                const int d = ct * 16 + r16;
                f16x8 bHi = *(const f16x8*)&vh[(size_t)d * N_ + k0];
                f16x8 bLo = *(const f16x8*)&vl[(size_t)d * N_ + k0];
                acc[ct] = __builtin_amdgcn_mfma_f32_16x16x32_f16(aHi, bHi, acc[ct], 0, 0, 0);
                acc[ct] = __builtin_amdgcn_mfma_f32_16x16x32_f16(aHi, bLo, acc[ct], 0, 0, 0);
                acc[ct] = __builtin_amdgcn_mfma_f32_16x16x32_f16(aLo, bHi, acc[ct], 0, 0, 0);
            }
        }
    }

#pragma unroll
    for (int ct = 0; ct < 4; ++ct) {
        const int c = h * HD_ + ct * 16 + r16;
#pragma unroll
        for (int j = 0; j < 4; ++j) {
            const int r = n0 + w * 16 + 4 * g + j;
            ctx[(size_t)(b * N_ + r) * C_ + c] = acc[ct][j];
        }
    }
}

// ---------------------------------------------------------------------------
// Kernel 4: proj_mfma — y = ctx @ Wproj + bproj + x via f16-split MFMA.
//   32 rows x 128 cols/block (grid 128x4 = 512 blocks, 2/CU), 4 waves each
//   owning 32 cols (2 ct); kt unrolled x2 with hoisted A loads (MLP).
// ---------------------------------------------------------------------------
__global__ __launch_bounds__(256) void proj_mfma(const float* __restrict__ ctx,
                                                 const float* __restrict__ x,
                                                 const _Float16* __restrict__ wp_hi,
                                                 const _Float16* __restrict__ wp_lo,
                                                 const float* __restrict__ bproj,
                                                 float* __restrict__ y) {
    const int tid = threadIdx.x;
    const int lane = tid & 63;
    const int w = tid >> 6;
    const int r16 = lane & 15;
    const int g = lane >> 4;
    const int row0 = blockIdx.x * 32;
    const int colw = blockIdx.y * 128 + w * 32;

    f32x4 acc[2][2] = {};

    const float* ar0 = ctx + (size_t)(row0 + r16) * C_;
    const float* ar1 = ctx + (size_t)(row0 + 16 + r16) * C_;

    for (int kt = 0; kt < 16; kt += 2) {
        // hoisted A loads for 2 sub-steps x 2 rows (MLP)
        float4 a0[2], a1[2], b0[2], b1[2];
#pragma unroll
        for (int u = 0; u < 2; ++u) {
            const int k0 = (kt + u) * 32 + 8 * g;
            a0[u] = *(const float4*)&ar0[k0];
            a1[u] = *(const float4*)&ar0[k0 + 4];
            b0[u] = *(const float4*)&ar1[k0];
            b1[u] = *(const float4*)&ar1[k0 + 4];
        }
#pragma unroll
        for (int u = 0; u < 2; ++u) {
            const int k0 = (kt + u) * 32 + 8 * g;
            f16x8 aHi0, aLo0, aHi1, aLo1;
            cvt_split(a0[u], a1[u], aHi0, aLo0);
            cvt_split(b0[u], b1[u], aHi1, aLo1);
#pragma unroll
            for (int ct = 0; ct < 2; ++ct) {
                const int c = colw + ct * 16 + r16;
                f16x8 bHi = *(const f16x8*)&wp_hi[(size_t)c * C_ + k0];
                f16x8 bLo = *(const f16x8*)&wp_lo[(size_t)c * C_ + k0];
                acc[0][ct] = __builtin_amdgcn_mfma_f32_16x16x32_f16(aHi0, bHi, acc[0][ct], 0, 0, 0);
                acc[0][ct] = __builtin_amdgcn_mfma_f32_16x16x32_f16(aHi0, bLo, acc[0][ct], 0, 0, 0);
                acc[0][ct] = __builtin_amdgcn_mfma_f32_16x16x32_f16(aLo0, bHi, acc[0][ct], 0, 0, 0);
                acc[1][ct] = __builtin_amdgcn_mfma_f32_16x16x32_f16(aHi1, bHi, acc[1][ct], 0, 0, 0);
                acc[1][ct] = __builtin_amdgcn_mfma_f32_16x16x32_f16(aHi1, bLo, acc[1][ct], 0, 0, 0);
                acc[1][ct] = __builtin_amdgcn_mfma_f32_16x16x32_f16(aLo1, bHi, acc[1][ct], 0, 0, 0);
            }
        }
    }

#pragma unroll
    for (int rt = 0; rt < 2; ++rt)
#pragma unroll
        for (int ct = 0; ct < 2; ++ct) {
            const int c = colw + ct * 16 + r16;
            const float bias = bproj[c];
#pragma unroll
            for (int j = 0; j < 4; ++j) {
                const int r = row0 + rt * 16 + 4 * g + j;
                y[(size_t)r * C_ + c] = acc[rt][ct][j] + bias + x[(size_t)r * C_ + c];
            }
        }
}

// ---------------------------------------------------------------------------
// Kernel 5: ln_kernel (unchanged)
// ---------------------------------------------------------------------------
__global__ __launch_bounds__(256) void ln_kernel(float* __restrict__ y,
                                                 const float* __restrict__ gamma,
                                                 const float* __restrict__ beta) {
    __shared__ float wsum[4], wsq[4];
    const int row = blockIdx.x;
    const int tid = threadIdx.x;
    const int lane = tid & 63;
    const int w = tid >> 6;

    float2 v = ((const float2*)(y + (size_t)row * C_))[tid];
    float s = v.x + v.y;
    float sq = v.x * v.x + v.y * v.y;
#pragma unroll
    for (int m = 1; m < 64; m <<= 1) {
        s += __shfl_xor(s, m, 64);
        sq += __shfl_xor(sq, m, 64);
    }
    if (lane == 0) { wsum[w] = s; wsq[w] = sq; }
    __syncthreads();
    float ts = wsum[0] + wsum[1] + wsum[2] + wsum[3];
    float tq = wsq[0] + wsq[1] + wsq[2] + wsq[3];
    float mu = ts * (1.0f / C_);
    float var = tq * (1.0f / C_) - mu * mu;
    float rstd = rsqrtf(var + LN_EPS_);

    float2 g = ((const float2*)gamma)[tid];
    float2 be = ((const float2*)beta)[tid];
    float2 o;
    o.x = (v.x - mu) * rstd * g.x + be.x;
    o.y = (v.y - mu) * rstd * g.y + be.y;
    ((float2*)(y + (size_t)row * C_))[tid] = o;
}

extern "C" void kernel_launch(void* const* d_in, const int* in_sizes, int n_in,
                              void* d_out, int out_size, void* d_ws, size_t ws_size,
                              hipStream_t stream) {
    const float* x     = (const float*)d_in[0];
    const float* Wqkv  = (const float*)d_in[1];
    const float* bqkv  = (const float*)d_in[2];
    const float* ow    = (const float*)d_in[3];
    const float* Wproj = (const float*)d_in[4];
    const float* bproj = (const float*)d_in[5];
    const float* gamma = (const float*)d_in[6];
    const float* beta  = (const float*)d_in[7];

    float* out  = (float*)d_out;
    float* y    = out;                                  // [B,N,C]
    float* attn = out + (size_t)B_ * N_ * C_;           // [B,H,N,N]
    float* qkv  = (float*)d_ws;                         // [B*N, 3C]  25 MB
    float* ctx  = qkv + (size_t)B_ * N_ * 3 * C_;       // [B*N, C]    8 MB

    // Wt_hi/Wt_lo overlay the attn output region (3 MB of 128 MB); consumed by
    // qkv_gemm_mfma, then rewritten by attn_scores.
    _Float16* wt_hi = (_Float16*)attn;
    _Float16* wt_lo = wt_hi + (size_t)(3 * C_) * C_;
    // Vt_hi/Vt_lo overlay the y region (8 MB exactly); consumed by pv_mfma,
    // then rewritten by proj_mfma.
    _Float16* vt_hi = (_Float16*)y;
    _Float16* vt_lo = vt_hi + (size_t)B_ * H_ * HD_ * N_;
    // wp_hi/wp_lo live in the ws tail after ctx (1 MB; ws is much larger).
    _Float16* wp_hi = (_Float16*)(ctx + (size_t)B_ * N_ * C_);
    _Float16* wp_lo = wp_hi + (size_t)C_ * C_;

    dim3 g0(3 * C_ / 64, C_ / 64);                      // (24, 8)
    wsplit_qkv<<<g0, 256, 0, stream>>>(Wqkv, wt_hi, wt_lo);

    dim3 gp(C_ / 64, C_ / 64);                          // (8, 8)
    wsplit_proj<<<gp, 256, 0, stream>>>(Wproj, wp_hi, wp_lo);

    dim3 g1(B_ * N_ / 32, 3 * C_ / 256);                // (128, 6)
    qkv_gemm_mfma<<<g1, 256, 0, stream>>>(x, wt_hi, wt_lo, bqkv, qkv);

    dim3 gv(N_ / 64, B_ * H_);                          // (16, 32)
    vsplit_v<<<gv, 256, 0, stream>>>(qkv, vt_hi, vt_lo);

    dim3 g2(N_ / 16, B_ * H_);                          // (64, 32)
    attn_scores<<<g2, 256, 0, stream>>>(qkv, ow, attn);

    dim3 g3(N_ / 64, B_ * H_);                          // (16, 32)
    pv_mfma<<<g3, 256, 0, stream>>>(attn, vt_hi, vt_lo, ctx);

    dim3 g4(B_ * N_ / 32, C_ / 128);                    // (128, 4)
    proj_mfma<<<g4, 256, 0, stream>>>(ctx, x, wp_hi, wp_lo, bproj, y);

    ln_kernel<<<B_ * N_, 256, 0, stream>>>(y, gamma, beta);
}

// Round 8
// 399.415 us; speedup vs baseline: 1.0578x; 1.0010x over previous
//
#include <hip/hip_runtime.h>
#include <math.h>

#define B_ 4
#define N_ 1024
#define C_ 512
#define H_ 8
#define HD_ 64
#define SCALE_ 0.125f
#define LN_EPS_ 1e-5f

typedef _Float16 f16x8 __attribute__((ext_vector_type(8)));
typedef float f32x4 __attribute__((ext_vector_type(4)));

// Split 8 fp32 (two float4) into f16 hi + f16 lo such that hi+lo ~= x (22-bit).
__device__ __forceinline__ void cvt_split(const float4& A, const float4& Bv,
                                          f16x8& hi, f16x8& lo) {
    float v[8] = {A.x, A.y, A.z, A.w, Bv.x, Bv.y, Bv.z, Bv.w};
#pragma unroll
    for (int i = 0; i < 8; ++i) {
        _Float16 h = (_Float16)v[i];
        hi[i] = h;
        lo[i] = (_Float16)(v[i] - (float)h);
    }
}

// ---------------------------------------------------------------------------
// Kernel 0: wsplit_qkv — transpose + f16-split Wqkv [512][1536] into
//   Wt_hi/Wt_lo [1536][512]. Lives in attn region (rewritten by attn_scores).
// ---------------------------------------------------------------------------
__global__ __launch_bounds__(256) void wsplit_qkv(const float* __restrict__ W,
                                                  _Float16* __restrict__ wt_hi,
                                                  _Float16* __restrict__ wt_lo) {
    __shared__ float tile[64][65];
    const int tid = threadIdx.x;
    const int n0 = blockIdx.x * 64;   // col of W  (row of Wt)
    const int k0 = blockIdx.y * 64;   // row of W  (col of Wt)
#pragma unroll
    for (int i = 0; i < 16; ++i) {
        int e = tid + i * 256;
        int kk = e >> 6, nn = e & 63;
        tile[kk][nn] = W[(size_t)(k0 + kk) * (3 * C_) + n0 + nn];
    }
    __syncthreads();
#pragma unroll
    for (int i = 0; i < 16; ++i) {
        int e = tid + i * 256;
        int n = e >> 6, k = e & 63;
        float v = tile[k][n];
        _Float16 h = (_Float16)v;
        wt_hi[(size_t)(n0 + n) * C_ + k0 + k] = h;
        wt_lo[(size_t)(n0 + n) * C_ + k0 + k] = (_Float16)(v - (float)h);
    }
}

// ---------------------------------------------------------------------------
// Kernel 0c: wsplit_proj — transpose + f16-split Wproj [512][512] into
//   wp_hi/wp_lo [512][512]. Lives in ws tail.
// ---------------------------------------------------------------------------
__global__ __launch_bounds__(256) void wsplit_proj(const float* __restrict__ W,
                                                   _Float16* __restrict__ wp_hi,
                                                   _Float16* __restrict__ wp_lo) {
    __shared__ float tile[64][65];
    const int tid = threadIdx.x;
    const int n0 = blockIdx.x * 64;
    const int k0 = blockIdx.y * 64;
#pragma unroll
    for (int i = 0; i < 16; ++i) {
        int e = tid + i * 256;
        int kk = e >> 6, nn = e & 63;
        tile[kk][nn] = W[(size_t)(k0 + kk) * C_ + n0 + nn];
    }
    __syncthreads();
#pragma unroll
    for (int i = 0; i < 16; ++i) {
        int e = tid + i * 256;
        int n = e >> 6, k = e & 63;
        float v = tile[k][n];
        _Float16 h = (_Float16)v;
        wp_hi[(size_t)(n0 + n) * C_ + k0 + k] = h;
        wp_lo[(size_t)(n0 + n) * C_ + k0 + k] = (_Float16)(v - (float)h);
    }
}

// ---------------------------------------------------------------------------
// Kernel 0b: vsplit_v — transpose + f16-split V (from qkv) into
//   Vt_hi/Vt_lo [B*H][HD][N]. Lives in y region (rewritten by proj_mfma).
// ---------------------------------------------------------------------------
__global__ __launch_bounds__(256) void vsplit_v(const float* __restrict__ qkv,
                                                _Float16* __restrict__ vt_hi,
                                                _Float16* __restrict__ vt_lo) {
    __shared__ float tile[64][65];
    const int tid = threadIdx.x;
    const int m0 = blockIdx.x * 64;
    const int bh = blockIdx.y;
    const int b = bh >> 3, h = bh & 7;
    const size_t RS = 3 * C_;
#pragma unroll
    for (int i = 0; i < 16; ++i) {
        int e = tid + i * 256;
        int mm = e >> 6, d = e & 63;
        tile[mm][d] = qkv[(size_t)(b * N_ + m0 + mm) * RS + 2 * C_ + h * HD_ + d];
    }
    __syncthreads();
#pragma unroll
    for (int i = 0; i < 16; ++i) {
        int e = tid + i * 256;
        int d = e >> 6, mm = e & 63;
        float v = tile[mm][d];
        _Float16 hh = (_Float16)v;
        size_t idx = ((size_t)bh * HD_ + d) * N_ + m0 + mm;
        vt_hi[idx] = hh;
        vt_lo[idx] = (_Float16)(v - (float)hh);
    }
}

// ---------------------------------------------------------------------------
// Kernel 1: qkv_gemm_mfma (unchanged — validated round 3)
// ---------------------------------------------------------------------------
__global__ __launch_bounds__(256) void qkv_gemm_mfma(const float* __restrict__ x,
                                                     const _Float16* __restrict__ wt_hi,
                                                     const _Float16* __restrict__ wt_lo,
                                                     const float* __restrict__ bqkv,
                                                     float* __restrict__ qkv) {
    const int tid = threadIdx.x;
    const int lane = tid & 63;
    const int w = tid >> 6;
    const int r16 = lane & 15;
    const int g = lane >> 4;
    const int row0 = blockIdx.x * 32;
    const int col0 = blockIdx.y * 256 + w * 64;

    f32x4 acc[2][4] = {};

    const float* xr0 = x + (size_t)(row0 + r16) * C_;
    const float* xr1 = x + (size_t)(row0 + 16 + r16) * C_;

    for (int kt = 0; kt < 16; ++kt) {
        const int k0 = kt * 32 + 8 * g;
        f16x8 aHi0, aLo0, aHi1, aLo1;
        {
            float4 a0 = *(const float4*)&xr0[k0];
            float4 a1 = *(const float4*)&xr0[k0 + 4];
            cvt_split(a0, a1, aHi0, aLo0);
            float4 b0 = *(const float4*)&xr1[k0];
            float4 b1 = *(const float4*)&xr1[k0 + 4];
            cvt_split(b0, b1, aHi1, aLo1);
        }
#pragma unroll
        for (int ct = 0; ct < 4; ++ct) {
            const int c = col0 + ct * 16 + r16;
            f16x8 bHi = *(const f16x8*)&wt_hi[(size_t)c * C_ + k0];
            f16x8 bLo = *(const f16x8*)&wt_lo[(size_t)c * C_ + k0];
            acc[0][ct] = __builtin_amdgcn_mfma_f32_16x16x32_f16(aHi0, bHi, acc[0][ct], 0, 0, 0);
            acc[0][ct] = __builtin_amdgcn_mfma_f32_16x16x32_f16(aHi0, bLo, acc[0][ct], 0, 0, 0);
            acc[0][ct] = __builtin_amdgcn_mfma_f32_16x16x32_f16(aLo0, bHi, acc[0][ct], 0, 0, 0);
            acc[1][ct] = __builtin_amdgcn_mfma_f32_16x16x32_f16(aHi1, bHi, acc[1][ct], 0, 0, 0);
            acc[1][ct] = __builtin_amdgcn_mfma_f32_16x16x32_f16(aHi1, bLo, acc[1][ct], 0, 0, 0);
            acc[1][ct] = __builtin_amdgcn_mfma_f32_16x16x32_f16(aLo1, bHi, acc[1][ct], 0, 0, 0);
        }
    }

#pragma unroll
    for (int rt = 0; rt < 2; ++rt)
#pragma unroll
        for (int ct = 0; ct < 4; ++ct) {
            const int c = col0 + ct * 16 + r16;
            const float bias = bqkv[c];
#pragma unroll
            for (int j = 0; j < 4; ++j) {
                const int r = row0 + rt * 16 + 4 * g + j;
                qkv[(size_t)r * (3 * C_) + c] = acc[rt][ct][j] + bias;
            }
        }
}

// ---------------------------------------------------------------------------
// Kernel 2: attn_scores (unchanged — validated round 2)
// ---------------------------------------------------------------------------
__global__ __launch_bounds__(256) void attn_scores(const float* __restrict__ qkv,
                                                   const float* __restrict__ ow_in,
                                                   float* __restrict__ attn) {
    __shared__ float smax[4][16];
    __shared__ float ssum[4][16];

    const int tid = threadIdx.x;
    const int lane = tid & 63;
    const int w = tid >> 6;           // wave 0..3 -> key cols [w*256, w*256+256)
    const int r16 = lane & 15;        // A row / B col / D col
    const int g = lane >> 4;          // k-group: k = 8g..8g+7 (+32 for kstep1)
    const int n0 = blockIdx.x * 16;   // query-row tile
    const int bh = blockIdx.y;
    const int b = bh >> 3, h = bh & 7;
    const size_t RS = 3 * C_;

    float w0 = ow_in[0], w1 = ow_in[1], w2 = ow_in[2];
    float wm = fmaxf(w0, fmaxf(w1, w2));
    float e0 = __expf(w0 - wm), e1 = __expf(w1 - wm), e2 = __expf(w2 - wm);
    float einv = 1.0f / (e0 + e1 + e2);
    float ow0 = e0 * einv, ow1 = e1 * einv, ow2 = e2 * einv;

    const float* qrow = qkv + (size_t)(b * N_ + n0 + r16) * RS + h * HD_;
    f16x8 aHi0, aLo0, aHi1, aLo1;
    {
        float4 qa = ((const float4*)qrow)[2 * g + 0];
        float4 qb = ((const float4*)qrow)[2 * g + 1];
        float4 qc = ((const float4*)qrow)[8 + 2 * g];
        float4 qd = ((const float4*)qrow)[9 + 2 * g];
        cvt_split(qa, qb, aHi0, aLo0);
        cvt_split(qc, qd, aHi1, aLo1);
    }

    float p[16][4];

    const float* kbase = qkv + (size_t)(b * N_) * RS + C_ + h * HD_;
#pragma unroll
    for (int t = 0; t < 16; ++t) {
        const int ct = w * 16 + t;
        const float* krow = kbase + (size_t)(ct * 16 + r16) * RS;
        float4 ka = ((const float4*)krow)[2 * g + 0];
        float4 kb = ((const float4*)krow)[2 * g + 1];
        float4 kc = ((const float4*)krow)[8 + 2 * g];
        float4 kd = ((const float4*)krow)[9 + 2 * g];
        f16x8 bHi0, bLo0, bHi1, bLo1;
        cvt_split(ka, kb, bHi0, bLo0);
        cvt_split(kc, kd, bHi1, bLo1);

        f32x4 acc = {0.f, 0.f, 0.f, 0.f};
        acc = __builtin_amdgcn_mfma_f32_16x16x32_f16(aHi0, bHi0, acc, 0, 0, 0);
        acc = __builtin_amdgcn_mfma_f32_16x16x32_f16(aHi0, bLo0, acc, 0, 0, 0);
        acc = __builtin_amdgcn_mfma_f32_16x16x32_f16(aLo0, bHi0, acc, 0, 0, 0);
        acc = __builtin_amdgcn_mfma_f32_16x16x32_f16(aHi1, bHi1, acc, 0, 0, 0);
        acc = __builtin_amdgcn_mfma_f32_16x16x32_f16(aHi1, bLo1, acc, 0, 0, 0);
        acc = __builtin_amdgcn_mfma_f32_16x16x32_f16(aLo1, bHi1, acc, 0, 0, 0);

#pragma unroll
        for (int j = 0; j < 4; ++j) {
            float s = acc[j] * SCALE_;
            p[t][j] = s * (ow0 + s * (ow1 + s * ow2));
        }
    }

    float rmax[4] = {-1e30f, -1e30f, -1e30f, -1e30f};
#pragma unroll
    for (int t = 0; t < 16; ++t)
#pragma unroll
        for (int j = 0; j < 4; ++j) rmax[j] = fmaxf(rmax[j], p[t][j]);
#pragma unroll
    for (int j = 0; j < 4; ++j)
#pragma unroll
        for (int m = 1; m < 16; m <<= 1)
            rmax[j] = fmaxf(rmax[j], __shfl_xor(rmax[j], m, 64));
    if (r16 == 0) {
#pragma unroll
        for (int j = 0; j < 4; ++j) smax[w][g * 4 + j] = rmax[j];
    }
    __syncthreads();
    float gm[4];
#pragma unroll
    for (int j = 0; j < 4; ++j) {
        int rr = g * 4 + j;
        gm[j] = fmaxf(fmaxf(smax[0][rr], smax[1][rr]),
                      fmaxf(smax[2][rr], smax[3][rr]));
    }

    float rsum[4] = {0.f, 0.f, 0.f, 0.f};
#pragma unroll
    for (int t = 0; t < 16; ++t)
#pragma unroll
        for (int j = 0; j < 4; ++j) {
            float e = __expf(p[t][j] - gm[j]);
            p[t][j] = e;
            rsum[j] += e;
        }
#pragma unroll
    for (int j = 0; j < 4; ++j)
#pragma unroll
        for (int m = 1; m < 16; m <<= 1)
            rsum[j] += __shfl_xor(rsum[j], m, 64);
    if (r16 == 0) {
#pragma unroll
        for (int j = 0; j < 4; ++j) ssum[w][g * 4 + j] = rsum[j];
    }
    __syncthreads();
    float inv[4];
#pragma unroll
    for (int j = 0; j < 4; ++j) {
        int rr = g * 4 + j;
        inv[j] = 1.0f / (ssum[0][rr] + ssum[1][rr] + ssum[2][rr] + ssum[3][rr]);
    }

    float* abase = attn + ((size_t)bh * N_ + n0 + 4 * g) * N_ + w * 256 + r16;
#pragma unroll
    for (int j = 0; j < 4; ++j) {
        float* arow = abase + (size_t)j * N_;
        float sc = inv[j];
#pragma unroll
        for (int t = 0; t < 16; ++t)
            arow[t * 16] = p[t][j] * sc;
    }
}

// ---------------------------------------------------------------------------
// Kernel 3: pv_mfma v3 — occupancy-retiled. Round-5 PMC: Occupancy 21%
//   (grid 512 = 2 blocks/CU), latency-bound. Now grid (N/16, B*H) = 2048
//   blocks; 4 waves split k (256 keys each) and partial sums reduce via LDS.
//   P loads 4-chunk-deep prefetch (8 in-flight 16B loads/lane).
// ---------------------------------------------------------------------------
__global__ __launch_bounds__(256) void pv_mfma(const float* __restrict__ attn,
                                               const _Float16* __restrict__ vt_hi,
                                               const _Float16* __restrict__ vt_lo,
                                               float* __restrict__ ctx) {
    __shared__ float red[4][16][68];   // [wave][row][d]  (68: 16B-aligned rows)

    const int tid = threadIdx.x;
    const int lane = tid & 63;
    const int w = tid >> 6;           // wave -> keys [w*256, w*256+256)
    const int r16 = lane & 15;        // A row = output row
    const int g = lane >> 4;          // k-group
    const int n0 = blockIdx.x * 16;
    const int bh = blockIdx.y;
    const int b = bh >> 3, h = bh & 7;

    // lane's P row pointer, offset to its k-slot within each 32-chunk
    const float* prow = attn + ((size_t)bh * N_ + n0 + r16) * N_ + w * 256 + 8 * g;
    const _Float16* vh = vt_hi + (size_t)bh * HD_ * N_ + w * 256 + 8 * g;
    const _Float16* vl = vt_lo + (size_t)bh * HD_ * N_ + w * 256 + 8 * g;

    f32x4 acc[4] = {};

#pragma unroll
    for (int grp = 0; grp < 2; ++grp) {
        // issue 8 P loads (4 chunks x 2 float4) before any use
        float4 p0[4], p1[4];
#pragma unroll
        for (int u = 0; u < 4; ++u) {
            const int k0 = (grp * 4 + u) * 32;
            p0[u] = *(const float4*)&prow[k0];
            p1[u] = *(const float4*)&prow[k0 + 4];
        }
#pragma unroll
        for (int u = 0; u < 4; ++u) {
            const int k0 = (grp * 4 + u) * 32;
            f16x8 aHi, aLo;
            cvt_split(p0[u], p1[u], aHi, aLo);
#pragma unroll
            for (int ct = 0; ct < 4; ++ct) {
                const int d = ct * 16 + r16;
                f16x8 bHi = *(const f16x8*)&vh[(size_t)d * N_ + k0];
                f16x8 bLo = *(const f16x8*)&vl[(size_t)d * N_ + k0];
                acc[ct] = __builtin_amdgcn_mfma_f32_16x16x32_f16(aHi, bHi, acc[ct], 0, 0, 0);
                acc[ct] = __builtin_amdgcn_mfma_f32_16x16x32_f16(aHi, bLo, acc[ct], 0, 0, 0);
                acc[ct] = __builtin_amdgcn_mfma_f32_16x16x32_f16(aLo, bHi, acc[ct], 0, 0, 0);
            }
        }
    }

    // write partials: D layout col = ct*16+r16, row = 4g+j
#pragma unroll
    for (int ct = 0; ct < 4; ++ct)
#pragma unroll
        for (int j = 0; j < 4; ++j)
            red[w][4 * g + j][ct * 16 + r16] = acc[ct][j];
    __syncthreads();

    // reduce 4 waves + coalesced float4 store
    const int e = tid * 4;
    const int row = e >> 6;
    const int d = e & 63;
    float4 s0 = *(const float4*)&red[0][row][d];
    float4 s1 = *(const float4*)&red[1][row][d];
    float4 s2 = *(const float4*)&red[2][row][d];
    float4 s3 = *(const float4*)&red[3][row][d];
    float4 o;
    o.x = s0.x + s1.x + s2.x + s3.x;
    o.y = s0.y + s1.y + s2.y + s3.y;
    o.z = s0.z + s1.z + s2.z + s3.z;
    o.w = s0.w + s1.w + s2.w + s3.w;
    *(float4*)&ctx[(size_t)(b * N_ + n0 + row) * C_ + h * HD_ + d] = o;
}

// ---------------------------------------------------------------------------
// Kernel 4: proj_mfma (unchanged — validated round 7)
// ---------------------------------------------------------------------------
__global__ __launch_bounds__(256) void proj_mfma(const float* __restrict__ ctx,
                                                 const float* __restrict__ x,
                                                 const _Float16* __restrict__ wp_hi,
                                                 const _Float16* __restrict__ wp_lo,
                                                 const float* __restrict__ bproj,
                                                 float* __restrict__ y) {
    const int tid = threadIdx.x;
    const int lane = tid & 63;
    const int w = tid >> 6;
    const int r16 = lane & 15;
    const int g = lane >> 4;
    const int row0 = blockIdx.x * 32;
    const int colw = blockIdx.y * 128 + w * 32;

    f32x4 acc[2][2] = {};

    const float* ar0 = ctx + (size_t)(row0 + r16) * C_;
    const float* ar1 = ctx + (size_t)(row0 + 16 + r16) * C_;

    for (int kt = 0; kt < 16; kt += 2) {
        float4 a0[2], a1[2], b0[2], b1[2];
#pragma unroll
        for (int u = 0; u < 2; ++u) {
            const int k0 = (kt + u) * 32 + 8 * g;
            a0[u] = *(const float4*)&ar0[k0];
            a1[u] = *(const float4*)&ar0[k0 + 4];
            b0[u] = *(const float4*)&ar1[k0];
            b1[u] = *(const float4*)&ar1[k0 + 4];
        }
#pragma unroll
        for (int u = 0; u < 2; ++u) {
            const int k0 = (kt + u) * 32 + 8 * g;
            f16x8 aHi0, aLo0, aHi1, aLo1;
            cvt_split(a0[u], a1[u], aHi0, aLo0);
            cvt_split(b0[u], b1[u], aHi1, aLo1);
#pragma unroll
            for (int ct = 0; ct < 2; ++ct) {
                const int c = colw + ct * 16 + r16;
                f16x8 bHi = *(const f16x8*)&wp_hi[(size_t)c * C_ + k0];
                f16x8 bLo = *(const f16x8*)&wp_lo[(size_t)c * C_ + k0];
                acc[0][ct] = __builtin_amdgcn_mfma_f32_16x16x32_f16(aHi0, bHi, acc[0][ct], 0, 0, 0);
                acc[0][ct] = __builtin_amdgcn_mfma_f32_16x16x32_f16(aHi0, bLo, acc[0][ct], 0, 0, 0);
                acc[0][ct] = __builtin_amdgcn_mfma_f32_16x16x32_f16(aLo0, bHi, acc[0][ct], 0, 0, 0);
                acc[1][ct] = __builtin_amdgcn_mfma_f32_16x16x32_f16(aHi1, bHi, acc[1][ct], 0, 0, 0);
                acc[1][ct] = __builtin_amdgcn_mfma_f32_16x16x32_f16(aHi1, bLo, acc[1][ct], 0, 0, 0);
                acc[1][ct] = __builtin_amdgcn_mfma_f32_16x16x32_f16(aLo1, bHi, acc[1][ct], 0, 0, 0);
            }
        }
    }

#pragma unroll
    for (int rt = 0; rt < 2; ++rt)
#pragma unroll
        for (int ct = 0; ct < 2; ++ct) {
            const int c = colw + ct * 16 + r16;
            const float bias = bproj[c];
#pragma unroll
            for (int j = 0; j < 4; ++j) {
                const int r = row0 + rt * 16 + 4 * g + j;
                y[(size_t)r * C_ + c] = acc[rt][ct][j] + bias + x[(size_t)r * C_ + c];
            }
        }
}

// ---------------------------------------------------------------------------
// Kernel 5: ln_kernel (unchanged)
// ---------------------------------------------------------------------------
__global__ __launch_bounds__(256) void ln_kernel(float* __restrict__ y,
                                                 const float* __restrict__ gamma,
                                                 const float* __restrict__ beta) {
    __shared__ float wsum[4], wsq[4];
    const int row = blockIdx.x;
    const int tid = threadIdx.x;
    const int lane = tid & 63;
    const int w = tid >> 6;

    float2 v = ((const float2*)(y + (size_t)row * C_))[tid];
    float s = v.x + v.y;
    float sq = v.x * v.x + v.y * v.y;
#pragma unroll
    for (int m = 1; m < 64; m <<= 1) {
        s += __shfl_xor(s, m, 64);
        sq += __shfl_xor(sq, m, 64);
    }
    if (lane == 0) { wsum[w] = s; wsq[w] = sq; }
    __syncthreads();
    float ts = wsum[0] + wsum[1] + wsum[2] + wsum[3];
    float tq = wsq[0] + wsq[1] + wsq[2] + wsq[3];
    float mu = ts * (1.0f / C_);
    float var = tq * (1.0f / C_) - mu * mu;
    float rstd = rsqrtf(var + LN_EPS_);

    float2 g = ((const float2*)gamma)[tid];
    float2 be = ((const float2*)beta)[tid];
    float2 o;
    o.x = (v.x - mu) * rstd * g.x + be.x;
    o.y = (v.y - mu) * rstd * g.y + be.y;
    ((float2*)(y + (size_t)row * C_))[tid] = o;
}

extern "C" void kernel_launch(void* const* d_in, const int* in_sizes, int n_in,
                              void* d_out, int out_size, void* d_ws, size_t ws_size,
                              hipStream_t stream) {
    const float* x     = (const float*)d_in[0];
    const float* Wqkv  = (const float*)d_in[1];
    const float* bqkv  = (const float*)d_in[2];
    const float* ow    = (const float*)d_in[3];
    const float* Wproj = (const float*)d_in[4];
    const float* bproj = (const float*)d_in[5];
    const float* gamma = (const float*)d_in[6];
    const float* beta  = (const float*)d_in[7];

    float* out  = (float*)d_out;
    float* y    = out;                                  // [B,N,C]
    float* attn = out + (size_t)B_ * N_ * C_;           // [B,H,N,N]
    float* qkv  = (float*)d_ws;                         // [B*N, 3C]  25 MB
    float* ctx  = qkv + (size_t)B_ * N_ * 3 * C_;       // [B*N, C]    8 MB

    // Wt_hi/Wt_lo overlay the attn output region (3 MB of 128 MB); consumed by
    // qkv_gemm_mfma, then rewritten by attn_scores.
    _Float16* wt_hi = (_Float16*)attn;
    _Float16* wt_lo = wt_hi + (size_t)(3 * C_) * C_;
    // Vt_hi/Vt_lo overlay the y region (8 MB exactly); consumed by pv_mfma,
    // then rewritten by proj_mfma.
    _Float16* vt_hi = (_Float16*)y;
    _Float16* vt_lo = vt_hi + (size_t)B_ * H_ * HD_ * N_;
    // wp_hi/wp_lo live in the ws tail after ctx (1 MB; ws is much larger).
    _Float16* wp_hi = (_Float16*)(ctx + (size_t)B_ * N_ * C_);
    _Float16* wp_lo = wp_hi + (size_t)C_ * C_;

    dim3 g0(3 * C_ / 64, C_ / 64);                      // (24, 8)
    wsplit_qkv<<<g0, 256, 0, stream>>>(Wqkv, wt_hi, wt_lo);

    dim3 gp(C_ / 64, C_ / 64);                          // (8, 8)
    wsplit_proj<<<gp, 256, 0, stream>>>(Wproj, wp_hi, wp_lo);

    dim3 g1(B_ * N_ / 32, 3 * C_ / 256);                // (128, 6)
    qkv_gemm_mfma<<<g1, 256, 0, stream>>>(x, wt_hi, wt_lo, bqkv, qkv);

    dim3 gv(N_ / 64, B_ * H_);                          // (16, 32)
    vsplit_v<<<gv, 256, 0, stream>>>(qkv, vt_hi, vt_lo);

    dim3 g2(N_ / 16, B_ * H_);                          // (64, 32)
    attn_scores<<<g2, 256, 0, stream>>>(qkv, ow, attn);

    dim3 g3(N_ / 16, B_ * H_);                          // (64, 32)
    pv_mfma<<<g3, 256, 0, stream>>>(attn, vt_hi, vt_lo, ctx);

    dim3 g4(B_ * N_ / 32, C_ / 128);                    // (128, 4)
    proj_mfma<<<g4, 256, 0, stream>>>(ctx, x, wp_hi, wp_lo, bproj, y);

    ln_kernel<<<B_ * N_, 256, 0, stream>>>(y, gamma, beta);
}

// Round 10
// 382.919 us; speedup vs baseline: 1.1034x; 1.0431x over previous
//
#include <hip/hip_runtime.h>
#include <math.h>

#define B_ 4
#define N_ 1024
#define C_ 512
#define H_ 8
#define HD_ 64
#define SCALE_ 0.125f
#define LN_EPS_ 1e-5f

typedef _Float16 f16x8 __attribute__((ext_vector_type(8)));
typedef float f32x4 __attribute__((ext_vector_type(4)));

// Split 8 fp32 (two float4) into f16 hi + f16 lo such that hi+lo ~= x (22-bit).
__device__ __forceinline__ void cvt_split(const float4& A, const float4& Bv,
                                          f16x8& hi, f16x8& lo) {
    float v[8] = {A.x, A.y, A.z, A.w, Bv.x, Bv.y, Bv.z, Bv.w};
#pragma unroll
    for (int i = 0; i < 8; ++i) {
        _Float16 h = (_Float16)v[i];
        hi[i] = h;
        lo[i] = (_Float16)(v[i] - (float)h);
    }
}

// ---------------------------------------------------------------------------
// Kernel 0: wsplit_qkv — transpose + f16-split Wqkv [512][1536] into
//   Wt_hi/Wt_lo [1536][512]. Lives in attn region (rewritten by attn_scores).
// ---------------------------------------------------------------------------
__global__ __launch_bounds__(256) void wsplit_qkv(const float* __restrict__ W,
                                                  _Float16* __restrict__ wt_hi,
                                                  _Float16* __restrict__ wt_lo) {
    __shared__ float tile[64][65];
    const int tid = threadIdx.x;
    const int n0 = blockIdx.x * 64;   // col of W  (row of Wt)
    const int k0 = blockIdx.y * 64;   // row of W  (col of Wt)
#pragma unroll
    for (int i = 0; i < 16; ++i) {
        int e = tid + i * 256;
        int kk = e >> 6, nn = e & 63;
        tile[kk][nn] = W[(size_t)(k0 + kk) * (3 * C_) + n0 + nn];
    }
    __syncthreads();
#pragma unroll
    for (int i = 0; i < 16; ++i) {
        int e = tid + i * 256;
        int n = e >> 6, k = e & 63;
        float v = tile[k][n];
        _Float16 h = (_Float16)v;
        wt_hi[(size_t)(n0 + n) * C_ + k0 + k] = h;
        wt_lo[(size_t)(n0 + n) * C_ + k0 + k] = (_Float16)(v - (float)h);
    }
}

// ---------------------------------------------------------------------------
// Kernel 0c: wsplit_proj — transpose + f16-split Wproj [512][512] into
//   wp_hi/wp_lo [512][512]. Lives in ws tail.
// ---------------------------------------------------------------------------
__global__ __launch_bounds__(256) void wsplit_proj(const float* __restrict__ W,
                                                   _Float16* __restrict__ wp_hi,
                                                   _Float16* __restrict__ wp_lo) {
    __shared__ float tile[64][65];
    const int tid = threadIdx.x;
    const int n0 = blockIdx.x * 64;
    const int k0 = blockIdx.y * 64;
#pragma unroll
    for (int i = 0; i < 16; ++i) {
        int e = tid + i * 256;
        int kk = e >> 6, nn = e & 63;
        tile[kk][nn] = W[(size_t)(k0 + kk) * C_ + n0 + nn];
    }
    __syncthreads();
#pragma unroll
    for (int i = 0; i < 16; ++i) {
        int e = tid + i * 256;
        int n = e >> 6, k = e & 63;
        float v = tile[k][n];
        _Float16 h = (_Float16)v;
        wp_hi[(size_t)(n0 + n) * C_ + k0 + k] = h;
        wp_lo[(size_t)(n0 + n) * C_ + k0 + k] = (_Float16)(v - (float)h);
    }
}

// ---------------------------------------------------------------------------
// Kernel 0b: vsplit_v — transpose + f16-split V (from qkv) into
//   Vt_hi/Vt_lo [B*H][HD][N]. Lives in y region (rewritten by proj_mfma).
// ---------------------------------------------------------------------------
__global__ __launch_bounds__(256) void vsplit_v(const float* __restrict__ qkv,
                                                _Float16* __restrict__ vt_hi,
                                                _Float16* __restrict__ vt_lo) {
    __shared__ float tile[64][65];
    const int tid = threadIdx.x;
    const int m0 = blockIdx.x * 64;
    const int bh = blockIdx.y;
    const int b = bh >> 3, h = bh & 7;
    const size_t RS = 3 * C_;
#pragma unroll
    for (int i = 0; i < 16; ++i) {
        int e = tid + i * 256;
        int mm = e >> 6, d = e & 63;
        tile[mm][d] = qkv[(size_t)(b * N_ + m0 + mm) * RS + 2 * C_ + h * HD_ + d];
    }
    __syncthreads();
#pragma unroll
    for (int i = 0; i < 16; ++i) {
        int e = tid + i * 256;
        int d = e >> 6, mm = e & 63;
        float v = tile[mm][d];
        _Float16 hh = (_Float16)v;
        size_t idx = ((size_t)bh * HD_ + d) * N_ + m0 + mm;
        vt_hi[idx] = hh;
        vt_lo[idx] = (_Float16)(v - (float)hh);
    }
}

// ---------------------------------------------------------------------------
// Kernel 1: qkv_gemm_mfma (unchanged — validated round 3)
// ---------------------------------------------------------------------------
__global__ __launch_bounds__(256) void qkv_gemm_mfma(const float* __restrict__ x,
                                                     const _Float16* __restrict__ wt_hi,
                                                     const _Float16* __restrict__ wt_lo,
                                                     const float* __restrict__ bqkv,
                                                     float* __restrict__ qkv) {
    const int tid = threadIdx.x;
    const int lane = tid & 63;
    const int w = tid >> 6;
    const int r16 = lane & 15;
    const int g = lane >> 4;
    const int row0 = blockIdx.x * 32;
    const int col0 = blockIdx.y * 256 + w * 64;

    f32x4 acc[2][4] = {};

    const float* xr0 = x + (size_t)(row0 + r16) * C_;
    const float* xr1 = x + (size_t)(row0 + 16 + r16) * C_;

    for (int kt = 0; kt < 16; ++kt) {
        const int k0 = kt * 32 + 8 * g;
        f16x8 aHi0, aLo0, aHi1, aLo1;
        {
            float4 a0 = *(const float4*)&xr0[k0];
            float4 a1 = *(const float4*)&xr0[k0 + 4];
            cvt_split(a0, a1, aHi0, aLo0);
            float4 b0 = *(const float4*)&xr1[k0];
            float4 b1 = *(const float4*)&xr1[k0 + 4];
            cvt_split(b0, b1, aHi1, aLo1);
        }
#pragma unroll
        for (int ct = 0; ct < 4; ++ct) {
            const int c = col0 + ct * 16 + r16;
            f16x8 bHi = *(const f16x8*)&wt_hi[(size_t)c * C_ + k0];
            f16x8 bLo = *(const f16x8*)&wt_lo[(size_t)c * C_ + k0];
            acc[0][ct] = __builtin_amdgcn_mfma_f32_16x16x32_f16(aHi0, bHi, acc[0][ct], 0, 0, 0);
            acc[0][ct] = __builtin_amdgcn_mfma_f32_16x16x32_f16(aHi0, bLo, acc[0][ct], 0, 0, 0);
            acc[0][ct] = __builtin_amdgcn_mfma_f32_16x16x32_f16(aLo0, bHi, acc[0][ct], 0, 0, 0);
            acc[1][ct] = __builtin_amdgcn_mfma_f32_16x16x32_f16(aHi1, bHi, acc[1][ct], 0, 0, 0);
            acc[1][ct] = __builtin_amdgcn_mfma_f32_16x16x32_f16(aHi1, bLo, acc[1][ct], 0, 0, 0);
            acc[1][ct] = __builtin_amdgcn_mfma_f32_16x16x32_f16(aLo1, bHi, acc[1][ct], 0, 0, 0);
        }
    }

#pragma unroll
    for (int rt = 0; rt < 2; ++rt)
#pragma unroll
        for (int ct = 0; ct < 4; ++ct) {
            const int c = col0 + ct * 16 + r16;
            const float bias = bqkv[c];
#pragma unroll
            for (int j = 0; j < 4; ++j) {
                const int r = row0 + rt * 16 + 4 * g + j;
                qkv[(size_t)r * (3 * C_) + c] = acc[rt][ct][j] + bias;
            }
        }
}

// ---------------------------------------------------------------------------
// Kernel 2: attn_scores — fused QK^T + polynomial + softmax + PV.
//   Phase 1 unchanged (validated round 2). Phase 2: each wave transposes its
//   in-register P slice (16 rows x 256 keys) into a PRIVATE LDS region
//   (two 128-key halves), reads A-fragments, MFMAs against Vt (pv-v3 loop),
//   then the pv-v3 LDS cross-wave reduce produces ctx. Eliminates pv_mfma's
//   98 MB P re-read and one launch. P values bit-identical to stored attn.
// ---------------------------------------------------------------------------
__global__ __launch_bounds__(256) void attn_scores(const float* __restrict__ qkv,
                                                   const float* __restrict__ ow_in,
                                                   const _Float16* __restrict__ vt_hi,
                                                   const _Float16* __restrict__ vt_lo,
                                                   float* __restrict__ attn,
                                                   float* __restrict__ ctx) {
    __shared__ float smax[4][16];
    __shared__ float ssum[4][16];
    __shared__ float Pw[4][16][140];   // per-wave private; 140 = 128 + 12 pad

    const int tid = threadIdx.x;
    const int lane = tid & 63;
    const int w = tid >> 6;           // wave 0..3 -> key cols [w*256, w*256+256)
    const int r16 = lane & 15;        // A row / B col / D col
    const int g = lane >> 4;          // k-group
    const int n0 = blockIdx.x * 16;   // query-row tile
    const int bh = blockIdx.y;
    const int b = bh >> 3, h = bh & 7;
    const size_t RS = 3 * C_;

    float w0 = ow_in[0], w1 = ow_in[1], w2 = ow_in[2];
    float wm = fmaxf(w0, fmaxf(w1, w2));
    float e0 = __expf(w0 - wm), e1 = __expf(w1 - wm), e2 = __expf(w2 - wm);
    float einv = 1.0f / (e0 + e1 + e2);
    float ow0 = e0 * einv, ow1 = e1 * einv, ow2 = e2 * einv;

    const float* qrow = qkv + (size_t)(b * N_ + n0 + r16) * RS + h * HD_;
    f16x8 aHi0, aLo0, aHi1, aLo1;
    {
        float4 qa = ((const float4*)qrow)[2 * g + 0];
        float4 qb = ((const float4*)qrow)[2 * g + 1];
        float4 qc = ((const float4*)qrow)[8 + 2 * g];
        float4 qd = ((const float4*)qrow)[9 + 2 * g];
        cvt_split(qa, qb, aHi0, aLo0);
        cvt_split(qc, qd, aHi1, aLo1);
    }

    float p[16][4];

    const float* kbase = qkv + (size_t)(b * N_) * RS + C_ + h * HD_;
#pragma unroll
    for (int t = 0; t < 16; ++t) {
        const int ct = w * 16 + t;
        const float* krow = kbase + (size_t)(ct * 16 + r16) * RS;
        float4 ka = ((const float4*)krow)[2 * g + 0];
        float4 kb = ((const float4*)krow)[2 * g + 1];
        float4 kc = ((const float4*)krow)[8 + 2 * g];
        float4 kd = ((const float4*)krow)[9 + 2 * g];
        f16x8 bHi0, bLo0, bHi1, bLo1;
        cvt_split(ka, kb, bHi0, bLo0);
        cvt_split(kc, kd, bHi1, bLo1);

        f32x4 acc = {0.f, 0.f, 0.f, 0.f};
        acc = __builtin_amdgcn_mfma_f32_16x16x32_f16(aHi0, bHi0, acc, 0, 0, 0);
        acc = __builtin_amdgcn_mfma_f32_16x16x32_f16(aHi0, bLo0, acc, 0, 0, 0);
        acc = __builtin_amdgcn_mfma_f32_16x16x32_f16(aLo0, bHi0, acc, 0, 0, 0);
        acc = __builtin_amdgcn_mfma_f32_16x16x32_f16(aHi1, bHi1, acc, 0, 0, 0);
        acc = __builtin_amdgcn_mfma_f32_16x16x32_f16(aHi1, bLo1, acc, 0, 0, 0);
        acc = __builtin_amdgcn_mfma_f32_16x16x32_f16(aLo1, bHi1, acc, 0, 0, 0);

#pragma unroll
        for (int j = 0; j < 4; ++j) {
            float s = acc[j] * SCALE_;
            p[t][j] = s * (ow0 + s * (ow1 + s * ow2));
        }
    }

    float rmax[4] = {-1e30f, -1e30f, -1e30f, -1e30f};
#pragma unroll
    for (int t = 0; t < 16; ++t)
#pragma unroll
        for (int j = 0; j < 4; ++j) rmax[j] = fmaxf(rmax[j], p[t][j]);
#pragma unroll
    for (int j = 0; j < 4; ++j)
#pragma unroll
        for (int m = 1; m < 16; m <<= 1)
            rmax[j] = fmaxf(rmax[j], __shfl_xor(rmax[j], m, 64));
    if (r16 == 0) {
#pragma unroll
        for (int j = 0; j < 4; ++j) smax[w][g * 4 + j] = rmax[j];
    }
    __syncthreads();
    float gm[4];
#pragma unroll
    for (int j = 0; j < 4; ++j) {
        int rr = g * 4 + j;
        gm[j] = fmaxf(fmaxf(smax[0][rr], smax[1][rr]),
                      fmaxf(smax[2][rr], smax[3][rr]));
    }

    float rsum[4] = {0.f, 0.f, 0.f, 0.f};
#pragma unroll
    for (int t = 0; t < 16; ++t)
#pragma unroll
        for (int j = 0; j < 4; ++j) {
            float e = __expf(p[t][j] - gm[j]);
            p[t][j] = e;
            rsum[j] += e;
        }
#pragma unroll
    for (int j = 0; j < 4; ++j)
#pragma unroll
        for (int m = 1; m < 16; m <<= 1)
            rsum[j] += __shfl_xor(rsum[j], m, 64);
    if (r16 == 0) {
#pragma unroll
        for (int j = 0; j < 4; ++j) ssum[w][g * 4 + j] = rsum[j];
    }
    __syncthreads();
    float inv[4];
#pragma unroll
    for (int j = 0; j < 4; ++j) {
        int rr = g * 4 + j;
        inv[j] = 1.0f / (ssum[0][rr] + ssum[1][rr] + ssum[2][rr] + ssum[3][rr]);
    }

    // normalize in-register: p becomes the final probabilities
#pragma unroll
    for (int t = 0; t < 16; ++t)
#pragma unroll
        for (int j = 0; j < 4; ++j)
            p[t][j] *= inv[j];

    // store attn (mandatory output) — same pattern as before
    float* abase = attn + ((size_t)bh * N_ + n0 + 4 * g) * N_ + w * 256 + r16;
#pragma unroll
    for (int j = 0; j < 4; ++j) {
        float* arow = abase + (size_t)j * N_;
#pragma unroll
        for (int t = 0; t < 16; ++t)
            arow[t * 16] = p[t][j];
    }

    // ---- Phase 2: PV from in-register P via per-wave LDS transpose ----
    const _Float16* vh = vt_hi + (size_t)bh * HD_ * N_ + w * 256 + 8 * g;
    const _Float16* vl = vt_lo + (size_t)bh * HD_ * N_ + w * 256 + 8 * g;
    float* pw = &Pw[w][0][0];          // this wave's private region

    f32x4 acc[4] = {};

#pragma unroll
    for (int half = 0; half < 2; ++half) {
        // transpose 8 t-tiles (128 keys) into [16 rows][140]
#pragma unroll
        for (int t8 = 0; t8 < 8; ++t8) {
            const int t = half * 8 + t8;
#pragma unroll
            for (int j = 0; j < 4; ++j)
                pw[(4 * g + j) * 140 + t8 * 16 + r16] = p[t][j];
        }
        // consume: 4 MFMA k-steps of 32 keys
#pragma unroll
        for (int kk = 0; kk < 4; ++kk) {
            float4 q0 = *(const float4*)&pw[r16 * 140 + kk * 32 + 8 * g];
            float4 q1 = *(const float4*)&pw[r16 * 140 + kk * 32 + 8 * g + 4];
            f16x8 aHi, aLo;
            cvt_split(q0, q1, aHi, aLo);
            const int kb = half * 128 + kk * 32;
#pragma unroll
            for (int ct = 0; ct < 4; ++ct) {
                const int d = ct * 16 + r16;
                f16x8 bHi = *(const f16x8*)&vh[(size_t)d * N_ + kb];
                f16x8 bLo = *(const f16x8*)&vl[(size_t)d * N_ + kb];
                acc[ct] = __builtin_amdgcn_mfma_f32_16x16x32_f16(aHi, bHi, acc[ct], 0, 0, 0);
                acc[ct] = __builtin_amdgcn_mfma_f32_16x16x32_f16(aHi, bLo, acc[ct], 0, 0, 0);
                acc[ct] = __builtin_amdgcn_mfma_f32_16x16x32_f16(aLo, bHi, acc[ct], 0, 0, 0);
            }
        }
    }

    // partials into own region (reuse pw; own reads are done in program order)
#pragma unroll
    for (int ct = 0; ct < 4; ++ct)
#pragma unroll
        for (int j = 0; j < 4; ++j)
            pw[(4 * g + j) * 68 + ct * 16 + r16] = acc[ct][j];
    __syncthreads();

    // cross-wave reduce + coalesced float4 store (pv-v3 epilogue)
    const int e = tid * 4;
    const int row = e >> 6;
    const int d = e & 63;
    const float* r0 = &Pw[0][0][0];
    const float* r1 = &Pw[1][0][0];
    const float* r2 = &Pw[2][0][0];
    const float* r3 = &Pw[3][0][0];
    float4 s0 = *(const float4*)&r0[row * 68 + d];
    float4 s1 = *(const float4*)&r1[row * 68 + d];
    float4 s2 = *(const float4*)&r2[row * 68 + d];
    float4 s3 = *(const float4*)&r3[row * 68 + d];
    float4 o;
    o.x = s0.x + s1.x + s2.x + s3.x;
    o.y = s0.y + s1.y + s2.y + s3.y;
    o.z = s0.z + s1.z + s2.z + s3.z;
    o.w = s0.w + s1.w + s2.w + s3.w;
    *(float4*)&ctx[(size_t)(b * N_ + n0 + row) * C_ + h * HD_ + d] = o;
}

// ---------------------------------------------------------------------------
// Kernel 4: proj_mfma (unchanged — validated round 7)
// ---------------------------------------------------------------------------
__global__ __launch_bounds__(256) void proj_mfma(const float* __restrict__ ctx,
                                                 const float* __restrict__ x,
                                                 const _Float16* __restrict__ wp_hi,
                                                 const _Float16* __restrict__ wp_lo,
                                                 const float* __restrict__ bproj,
                                                 float* __restrict__ y) {
    const int tid = threadIdx.x;
    const int lane = tid & 63;
    const int w = tid >> 6;
    const int r16 = lane & 15;
    const int g = lane >> 4;
    const int row0 = blockIdx.x * 32;
    const int colw = blockIdx.y * 128 + w * 32;

    f32x4 acc[2][2] = {};

    const float* ar0 = ctx + (size_t)(row0 + r16) * C_;
    const float* ar1 = ctx + (size_t)(row0 + 16 + r16) * C_;

    for (int kt = 0; kt < 16; kt += 2) {
        float4 a0[2], a1[2], b0[2], b1[2];
#pragma unroll
        for (int u = 0; u < 2; ++u) {
            const int k0 = (kt + u) * 32 + 8 * g;
            a0[u] = *(const float4*)&ar0[k0];
            a1[u] = *(const float4*)&ar0[k0 + 4];
            b0[u] = *(const float4*)&ar1[k0];
            b1[u] = *(const float4*)&ar1[k0 + 4];
        }
#pragma unroll
        for (int u = 0; u < 2; ++u) {
            const int k0 = (kt + u) * 32 + 8 * g;
            f16x8 aHi0, aLo0, aHi1, aLo1;
            cvt_split(a0[u], a1[u], aHi0, aLo0);
            cvt_split(b0[u], b1[u], aHi1, aLo1);
#pragma unroll
            for (int ct = 0; ct < 2; ++ct) {
                const int c = colw + ct * 16 + r16;
                f16x8 bHi = *(const f16x8*)&wp_hi[(size_t)c * C_ + k0];
                f16x8 bLo = *(const f16x8*)&wp_lo[(size_t)c * C_ + k0];
                acc[0][ct] = __builtin_amdgcn_mfma_f32_16x16x32_f16(aHi0, bHi, acc[0][ct], 0, 0, 0);
                acc[0][ct] = __builtin_amdgcn_mfma_f32_16x16x32_f16(aHi0, bLo, acc[0][ct], 0, 0, 0);
                acc[0][ct] = __builtin_amdgcn_mfma_f32_16x16x32_f16(aLo0, bHi, acc[0][ct], 0, 0, 0);
                acc[1][ct] = __builtin_amdgcn_mfma_f32_16x16x32_f16(aHi1, bHi, acc[1][ct], 0, 0, 0);
                acc[1][ct] = __builtin_amdgcn_mfma_f32_16x16x32_f16(aHi1, bLo, acc[1][ct], 0, 0, 0);
                acc[1][ct] = __builtin_amdgcn_mfma_f32_16x16x32_f16(aLo1, bHi, acc[1][ct], 0, 0, 0);
            }
        }
    }

#pragma unroll
    for (int rt = 0; rt < 2; ++rt)
#pragma unroll
        for (int ct = 0; ct < 2; ++ct) {
            const int c = colw + ct * 16 + r16;
            const float bias = bproj[c];
#pragma unroll
            for (int j = 0; j < 4; ++j) {
                const int r = row0 + rt * 16 + 4 * g + j;
                y[(size_t)r * C_ + c] = acc[rt][ct][j] + bias + x[(size_t)r * C_ + c];
            }
        }
}

// ---------------------------------------------------------------------------
// Kernel 5: ln_kernel (unchanged)
// ---------------------------------------------------------------------------
__global__ __launch_bounds__(256) void ln_kernel(float* __restrict__ y,
                                                 const float* __restrict__ gamma,
                                                 const float* __restrict__ beta) {
    __shared__ float wsum[4], wsq[4];
    const int row = blockIdx.x;
    const int tid = threadIdx.x;
    const int lane = tid & 63;
    const int w = tid >> 6;

    float2 v = ((const float2*)(y + (size_t)row * C_))[tid];
    float s = v.x + v.y;
    float sq = v.x * v.x + v.y * v.y;
#pragma unroll
    for (int m = 1; m < 64; m <<= 1) {
        s += __shfl_xor(s, m, 64);
        sq += __shfl_xor(sq, m, 64);
    }
    if (lane == 0) { wsum[w] = s; wsq[w] = sq; }
    __syncthreads();
    float ts = wsum[0] + wsum[1] + wsum[2] + wsum[3];
    float tq = wsq[0] + wsq[1] + wsq[2] + wsq[3];
    float mu = ts * (1.0f / C_);
    float var = tq * (1.0f / C_) - mu * mu;
    float rstd = rsqrtf(var + LN_EPS_);

    float2 g = ((const float2*)gamma)[tid];
    float2 be = ((const float2*)beta)[tid];
    float2 o;
    o.x = (v.x - mu) * rstd * g.x + be.x;
    o.y = (v.y - mu) * rstd * g.y + be.y;
    ((float2*)(y + (size_t)row * C_))[tid] = o;
}

extern "C" void kernel_launch(void* const* d_in, const int* in_sizes, int n_in,
                              void* d_out, int out_size, void* d_ws, size_t ws_size,
                              hipStream_t stream) {
    const float* x     = (const float*)d_in[0];
    const float* Wqkv  = (const float*)d_in[1];
    const float* bqkv  = (const float*)d_in[2];
    const float* ow    = (const float*)d_in[3];
    const float* Wproj = (const float*)d_in[4];
    const float* bproj = (const float*)d_in[5];
    const float* gamma = (const float*)d_in[6];
    const float* beta  = (const float*)d_in[7];

    float* out  = (float*)d_out;
    float* y    = out;                                  // [B,N,C]
    float* attn = out + (size_t)B_ * N_ * C_;           // [B,H,N,N]
    float* qkv  = (float*)d_ws;                         // [B*N, 3C]  25 MB
    float* ctx  = qkv + (size_t)B_ * N_ * 3 * C_;       // [B*N, C]    8 MB

    // Wt_hi/Wt_lo overlay the attn output region (3 MB of 128 MB); consumed by
    // qkv_gemm_mfma, then rewritten by attn_scores.
    _Float16* wt_hi = (_Float16*)attn;
    _Float16* wt_lo = wt_hi + (size_t)(3 * C_) * C_;
    // Vt_hi/Vt_lo overlay the y region (8 MB exactly); consumed by attn_scores
    // (fused PV), then rewritten by proj_mfma.
    _Float16* vt_hi = (_Float16*)y;
    _Float16* vt_lo = vt_hi + (size_t)B_ * H_ * HD_ * N_;
    // wp_hi/wp_lo live in the ws tail after ctx (1 MB; ws is much larger).
    _Float16* wp_hi = (_Float16*)(ctx + (size_t)B_ * N_ * C_);
    _Float16* wp_lo = wp_hi + (size_t)C_ * C_;

    dim3 g0(3 * C_ / 64, C_ / 64);                      // (24, 8)
    wsplit_qkv<<<g0, 256, 0, stream>>>(Wqkv, wt_hi, wt_lo);

    dim3 gp(C_ / 64, C_ / 64);                          // (8, 8)
    wsplit_proj<<<gp, 256, 0, stream>>>(Wproj, wp_hi, wp_lo);

    dim3 g1(B_ * N_ / 32, 3 * C_ / 256);                // (128, 6)
    qkv_gemm_mfma<<<g1, 256, 0, stream>>>(x, wt_hi, wt_lo, bqkv, qkv);

    dim3 gv(N_ / 64, B_ * H_);                          // (16, 32)
    vsplit_v<<<gv, 256, 0, stream>>>(qkv, vt_hi, vt_lo);

    dim3 g2(N_ / 16, B_ * H_);                          // (64, 32)
    attn_scores<<<g2, 256, 0, stream>>>(qkv, ow, vt_hi, vt_lo, attn, ctx);

    dim3 g4(B_ * N_ / 32, C_ / 128);                    // (128, 4)
    proj_mfma<<<g4, 256, 0, stream>>>(ctx, x, wp_hi, wp_lo, bproj, y);

    ln_kernel<<<B_ * N_, 256, 0, stream>>>(y, gamma, beta);
}

// Round 11
// 382.022 us; speedup vs baseline: 1.1059x; 1.0023x over previous
//
#include <hip/hip_runtime.h>
#include <math.h>

#define B_ 4
#define N_ 1024
#define C_ 512
#define H_ 8
#define HD_ 64
#define SCALE_ 0.125f
#define LN_EPS_ 1e-5f

typedef _Float16 f16x8 __attribute__((ext_vector_type(8)));
typedef float f32x4 __attribute__((ext_vector_type(4)));

// Split 8 fp32 (two float4) into f16 hi + f16 lo such that hi+lo ~= x (22-bit).
__device__ __forceinline__ void cvt_split(const float4& A, const float4& Bv,
                                          f16x8& hi, f16x8& lo) {
    float v[8] = {A.x, A.y, A.z, A.w, Bv.x, Bv.y, Bv.z, Bv.w};
#pragma unroll
    for (int i = 0; i < 8; ++i) {
        _Float16 h = (_Float16)v[i];
        hi[i] = h;
        lo[i] = (_Float16)(v[i] - (float)h);
    }
}

// ---------------------------------------------------------------------------
// Kernel 0: wsplit_qkv — transpose + f16-split Wqkv [512][1536] into
//   Wt_hi/Wt_lo [1536][512]. Lives in attn region (rewritten by attn_scores).
// ---------------------------------------------------------------------------
__global__ __launch_bounds__(256) void wsplit_qkv(const float* __restrict__ W,
                                                  _Float16* __restrict__ wt_hi,
                                                  _Float16* __restrict__ wt_lo) {
    __shared__ float tile[64][65];
    const int tid = threadIdx.x;
    const int n0 = blockIdx.x * 64;   // col of W  (row of Wt)
    const int k0 = blockIdx.y * 64;   // row of W  (col of Wt)
#pragma unroll
    for (int i = 0; i < 16; ++i) {
        int e = tid + i * 256;
        int kk = e >> 6, nn = e & 63;
        tile[kk][nn] = W[(size_t)(k0 + kk) * (3 * C_) + n0 + nn];
    }
    __syncthreads();
#pragma unroll
    for (int i = 0; i < 16; ++i) {
        int e = tid + i * 256;
        int n = e >> 6, k = e & 63;
        float v = tile[k][n];
        _Float16 h = (_Float16)v;
        wt_hi[(size_t)(n0 + n) * C_ + k0 + k] = h;
        wt_lo[(size_t)(n0 + n) * C_ + k0 + k] = (_Float16)(v - (float)h);
    }
}

// ---------------------------------------------------------------------------
// Kernel 0c: wsplit_proj — transpose + f16-split Wproj [512][512] into
//   wp_hi/wp_lo [512][512]. Lives in ws tail.
// ---------------------------------------------------------------------------
__global__ __launch_bounds__(256) void wsplit_proj(const float* __restrict__ W,
                                                   _Float16* __restrict__ wp_hi,
                                                   _Float16* __restrict__ wp_lo) {
    __shared__ float tile[64][65];
    const int tid = threadIdx.x;
    const int n0 = blockIdx.x * 64;
    const int k0 = blockIdx.y * 64;
#pragma unroll
    for (int i = 0; i < 16; ++i) {
        int e = tid + i * 256;
        int kk = e >> 6, nn = e & 63;
        tile[kk][nn] = W[(size_t)(k0 + kk) * C_ + n0 + nn];
    }
    __syncthreads();
#pragma unroll
    for (int i = 0; i < 16; ++i) {
        int e = tid + i * 256;
        int n = e >> 6, k = e & 63;
        float v = tile[k][n];
        _Float16 h = (_Float16)v;
        wp_hi[(size_t)(n0 + n) * C_ + k0 + k] = h;
        wp_lo[(size_t)(n0 + n) * C_ + k0 + k] = (_Float16)(v - (float)h);
    }
}

// ---------------------------------------------------------------------------
// Kernel 0b: vsplit_v — transpose + f16-split V (from qkv) into
//   Vt_hi/Vt_lo [B*H][HD][N]. Lives in y region (rewritten by proj_mfma).
// ---------------------------------------------------------------------------
__global__ __launch_bounds__(256) void vsplit_v(const float* __restrict__ qkv,
                                                _Float16* __restrict__ vt_hi,
                                                _Float16* __restrict__ vt_lo) {
    __shared__ float tile[64][65];
    const int tid = threadIdx.x;
    const int m0 = blockIdx.x * 64;
    const int bh = blockIdx.y;
    const int b = bh >> 3, h = bh & 7;
    const size_t RS = 3 * C_;
#pragma unroll
    for (int i = 0; i < 16; ++i) {
        int e = tid + i * 256;
        int mm = e >> 6, d = e & 63;
        tile[mm][d] = qkv[(size_t)(b * N_ + m0 + mm) * RS + 2 * C_ + h * HD_ + d];
    }
    __syncthreads();
#pragma unroll
    for (int i = 0; i < 16; ++i) {
        int e = tid + i * 256;
        int d = e >> 6, mm = e & 63;
        float v = tile[mm][d];
        _Float16 hh = (_Float16)v;
        size_t idx = ((size_t)bh * HD_ + d) * N_ + m0 + mm;
        vt_hi[idx] = hh;
        vt_lo[idx] = (_Float16)(v - (float)hh);
    }
}

// ---------------------------------------------------------------------------
// Kernel 1: qkv_gemm_mfma (unchanged — validated round 3)
// ---------------------------------------------------------------------------
__global__ __launch_bounds__(256) void qkv_gemm_mfma(const float* __restrict__ x,
                                                     const _Float16* __restrict__ wt_hi,
                                                     const _Float16* __restrict__ wt_lo,
                                                     const float* __restrict__ bqkv,
                                                     float* __restrict__ qkv) {
    const int tid = threadIdx.x;
    const int lane = tid & 63;
    const int w = tid >> 6;
    const int r16 = lane & 15;
    const int g = lane >> 4;
    const int row0 = blockIdx.x * 32;
    const int col0 = blockIdx.y * 256 + w * 64;

    f32x4 acc[2][4] = {};

    const float* xr0 = x + (size_t)(row0 + r16) * C_;
    const float* xr1 = x + (size_t)(row0 + 16 + r16) * C_;

    for (int kt = 0; kt < 16; ++kt) {
        const int k0 = kt * 32 + 8 * g;
        f16x8 aHi0, aLo0, aHi1, aLo1;
        {
            float4 a0 = *(const float4*)&xr0[k0];
            float4 a1 = *(const float4*)&xr0[k0 + 4];
            cvt_split(a0, a1, aHi0, aLo0);
            float4 b0 = *(const float4*)&xr1[k0];
            float4 b1 = *(const float4*)&xr1[k0 + 4];
            cvt_split(b0, b1, aHi1, aLo1);
        }
#pragma unroll
        for (int ct = 0; ct < 4; ++ct) {
            const int c = col0 + ct * 16 + r16;
            f16x8 bHi = *(const f16x8*)&wt_hi[(size_t)c * C_ + k0];
            f16x8 bLo = *(const f16x8*)&wt_lo[(size_t)c * C_ + k0];
            acc[0][ct] = __builtin_amdgcn_mfma_f32_16x16x32_f16(aHi0, bHi, acc[0][ct], 0, 0, 0);
            acc[0][ct] = __builtin_amdgcn_mfma_f32_16x16x32_f16(aHi0, bLo, acc[0][ct], 0, 0, 0);
            acc[0][ct] = __builtin_amdgcn_mfma_f32_16x16x32_f16(aLo0, bHi, acc[0][ct], 0, 0, 0);
            acc[1][ct] = __builtin_amdgcn_mfma_f32_16x16x32_f16(aHi1, bHi, acc[1][ct], 0, 0, 0);
            acc[1][ct] = __builtin_amdgcn_mfma_f32_16x16x32_f16(aHi1, bLo, acc[1][ct], 0, 0, 0);
            acc[1][ct] = __builtin_amdgcn_mfma_f32_16x16x32_f16(aLo1, bHi, acc[1][ct], 0, 0, 0);
        }
    }

#pragma unroll
    for (int rt = 0; rt < 2; ++rt)
#pragma unroll
        for (int ct = 0; ct < 4; ++ct) {
            const int c = col0 + ct * 16 + r16;
            const float bias = bqkv[c];
#pragma unroll
            for (int j = 0; j < 4; ++j) {
                const int r = row0 + rt * 16 + 4 * g + j;
                qkv[(size_t)r * (3 * C_) + c] = acc[rt][ct][j] + bias;
            }
        }
}

// ---------------------------------------------------------------------------
// Kernel 2: attn_scores — fused QK^T + polynomial + softmax + PV.
//   Round-11 change: attn stored COALESCED from the Pw LDS transpose
//   (16 float4 stores/lane instead of 64 scalar stride-64B stores).
//   Pw[row][c] == attn[n0+row][w*256 + half*128 + c] exactly.
// ---------------------------------------------------------------------------
__global__ __launch_bounds__(256) void attn_scores(const float* __restrict__ qkv,
                                                   const float* __restrict__ ow_in,
                                                   const _Float16* __restrict__ vt_hi,
                                                   const _Float16* __restrict__ vt_lo,
                                                   float* __restrict__ attn,
                                                   float* __restrict__ ctx) {
    __shared__ float smax[4][16];
    __shared__ float ssum[4][16];
    __shared__ float Pw[4][16][140];   // per-wave private; 140 = 128 + 12 pad

    const int tid = threadIdx.x;
    const int lane = tid & 63;
    const int w = tid >> 6;           // wave 0..3 -> key cols [w*256, w*256+256)
    const int r16 = lane & 15;        // A row / B col / D col
    const int g = lane >> 4;          // k-group
    const int n0 = blockIdx.x * 16;   // query-row tile
    const int bh = blockIdx.y;
    const int b = bh >> 3, h = bh & 7;
    const size_t RS = 3 * C_;

    float w0 = ow_in[0], w1 = ow_in[1], w2 = ow_in[2];
    float wm = fmaxf(w0, fmaxf(w1, w2));
    float e0 = __expf(w0 - wm), e1 = __expf(w1 - wm), e2 = __expf(w2 - wm);
    float einv = 1.0f / (e0 + e1 + e2);
    float ow0 = e0 * einv, ow1 = e1 * einv, ow2 = e2 * einv;

    const float* qrow = qkv + (size_t)(b * N_ + n0 + r16) * RS + h * HD_;
    f16x8 aHi0, aLo0, aHi1, aLo1;
    {
        float4 qa = ((const float4*)qrow)[2 * g + 0];
        float4 qb = ((const float4*)qrow)[2 * g + 1];
        float4 qc = ((const float4*)qrow)[8 + 2 * g];
        float4 qd = ((const float4*)qrow)[9 + 2 * g];
        cvt_split(qa, qb, aHi0, aLo0);
        cvt_split(qc, qd, aHi1, aLo1);
    }

    float p[16][4];

    const float* kbase = qkv + (size_t)(b * N_) * RS + C_ + h * HD_;
#pragma unroll
    for (int t = 0; t < 16; ++t) {
        const int ct = w * 16 + t;
        const float* krow = kbase + (size_t)(ct * 16 + r16) * RS;
        float4 ka = ((const float4*)krow)[2 * g + 0];
        float4 kb = ((const float4*)krow)[2 * g + 1];
        float4 kc = ((const float4*)krow)[8 + 2 * g];
        float4 kd = ((const float4*)krow)[9 + 2 * g];
        f16x8 bHi0, bLo0, bHi1, bLo1;
        cvt_split(ka, kb, bHi0, bLo0);
        cvt_split(kc, kd, bHi1, bLo1);

        f32x4 acc = {0.f, 0.f, 0.f, 0.f};
        acc = __builtin_amdgcn_mfma_f32_16x16x32_f16(aHi0, bHi0, acc, 0, 0, 0);
        acc = __builtin_amdgcn_mfma_f32_16x16x32_f16(aHi0, bLo0, acc, 0, 0, 0);
        acc = __builtin_amdgcn_mfma_f32_16x16x32_f16(aLo0, bHi0, acc, 0, 0, 0);
        acc = __builtin_amdgcn_mfma_f32_16x16x32_f16(aHi1, bHi1, acc, 0, 0, 0);
        acc = __builtin_amdgcn_mfma_f32_16x16x32_f16(aHi1, bLo1, acc, 0, 0, 0);
        acc = __builtin_amdgcn_mfma_f32_16x16x32_f16(aLo1, bHi1, acc, 0, 0, 0);

#pragma unroll
        for (int j = 0; j < 4; ++j) {
            float s = acc[j] * SCALE_;
            p[t][j] = s * (ow0 + s * (ow1 + s * ow2));
        }
    }

    float rmax[4] = {-1e30f, -1e30f, -1e30f, -1e30f};
#pragma unroll
    for (int t = 0; t < 16; ++t)
#pragma unroll
        for (int j = 0; j < 4; ++j) rmax[j] = fmaxf(rmax[j], p[t][j]);
#pragma unroll
    for (int j = 0; j < 4; ++j)
#pragma unroll
        for (int m = 1; m < 16; m <<= 1)
            rmax[j] = fmaxf(rmax[j], __shfl_xor(rmax[j], m, 64));
    if (r16 == 0) {
#pragma unroll
        for (int j = 0; j < 4; ++j) smax[w][g * 4 + j] = rmax[j];
    }
    __syncthreads();
    float gm[4];
#pragma unroll
    for (int j = 0; j < 4; ++j) {
        int rr = g * 4 + j;
        gm[j] = fmaxf(fmaxf(smax[0][rr], smax[1][rr]),
                      fmaxf(smax[2][rr], smax[3][rr]));
    }

    float rsum[4] = {0.f, 0.f, 0.f, 0.f};
#pragma unroll
    for (int t = 0; t < 16; ++t)
#pragma unroll
        for (int j = 0; j < 4; ++j) {
            float e = __expf(p[t][j] - gm[j]);
            p[t][j] = e;
            rsum[j] += e;
        }
#pragma unroll
    for (int j = 0; j < 4; ++j)
#pragma unroll
        for (int m = 1; m < 16; m <<= 1)
            rsum[j] += __shfl_xor(rsum[j], m, 64);
    if (r16 == 0) {
#pragma unroll
        for (int j = 0; j < 4; ++j) ssum[w][g * 4 + j] = rsum[j];
    }
    __syncthreads();
    float inv[4];
#pragma unroll
    for (int j = 0; j < 4; ++j) {
        int rr = g * 4 + j;
        inv[j] = 1.0f / (ssum[0][rr] + ssum[1][rr] + ssum[2][rr] + ssum[3][rr]);
    }

    // normalize in-register: p becomes the final probabilities
#pragma unroll
    for (int t = 0; t < 16; ++t)
#pragma unroll
        for (int j = 0; j < 4; ++j)
            p[t][j] *= inv[j];

    // ---- Phase 2: PV + coalesced attn store via per-wave LDS transpose ----
    const _Float16* vh = vt_hi + (size_t)bh * HD_ * N_ + w * 256 + 8 * g;
    const _Float16* vl = vt_lo + (size_t)bh * HD_ * N_ + w * 256 + 8 * g;
    float* pw = &Pw[w][0][0];          // this wave's private region

    f32x4 acc[4] = {};

#pragma unroll
    for (int half = 0; half < 2; ++half) {
        // transpose 8 t-tiles (128 keys) into [16 rows][140]
#pragma unroll
        for (int t8 = 0; t8 < 8; ++t8) {
            const int t = half * 8 + t8;
#pragma unroll
            for (int j = 0; j < 4; ++j)
                pw[(4 * g + j) * 140 + t8 * 16 + r16] = p[t][j];
        }
        // consume: 4 MFMA k-steps of 32 keys
#pragma unroll
        for (int kk = 0; kk < 4; ++kk) {
            float4 q0 = *(const float4*)&pw[r16 * 140 + kk * 32 + 8 * g];
            float4 q1 = *(const float4*)&pw[r16 * 140 + kk * 32 + 8 * g + 4];
            f16x8 aHi, aLo;
            cvt_split(q0, q1, aHi, aLo);
            const int kb = half * 128 + kk * 32;
#pragma unroll
            for (int ct = 0; ct < 4; ++ct) {
                const int d = ct * 16 + r16;
                f16x8 bHi = *(const f16x8*)&vh[(size_t)d * N_ + kb];
                f16x8 bLo = *(const f16x8*)&vl[(size_t)d * N_ + kb];
                acc[ct] = __builtin_amdgcn_mfma_f32_16x16x32_f16(aHi, bHi, acc[ct], 0, 0, 0);
                acc[ct] = __builtin_amdgcn_mfma_f32_16x16x32_f16(aHi, bLo, acc[ct], 0, 0, 0);
                acc[ct] = __builtin_amdgcn_mfma_f32_16x16x32_f16(aLo, bHi, acc[ct], 0, 0, 0);
            }
        }
        // coalesced attn store of this half from LDS:
        // Pw[row][c] == attn[n0+row][w*256 + half*128 + c]
#pragma unroll
        for (int it = 0; it < 8; ++it) {
            const int f = it * 64 + lane;      // float4 index in 16x128 tile
            const int row = f >> 5;             // 0..15
            const int c4 = (f & 31) * 4;        // 0..124
            float4 v4 = *(const float4*)&pw[row * 140 + c4];
            *(float4*)&attn[((size_t)bh * N_ + n0 + row) * N_ + w * 256 + half * 128 + c4] = v4;
        }
    }

    // partials into own region (reuse pw; own reads are done in program order)
#pragma unroll
    for (int ct = 0; ct < 4; ++ct)
#pragma unroll
        for (int j = 0; j < 4; ++j)
            pw[(4 * g + j) * 68 + ct * 16 + r16] = acc[ct][j];
    __syncthreads();

    // cross-wave reduce + coalesced float4 store (pv-v3 epilogue)
    const int e = tid * 4;
    const int row = e >> 6;
    const int d = e & 63;
    const float* r0 = &Pw[0][0][0];
    const float* r1 = &Pw[1][0][0];
    const float* r2 = &Pw[2][0][0];
    const float* r3 = &Pw[3][0][0];
    float4 s0 = *(const float4*)&r0[row * 68 + d];
    float4 s1 = *(const float4*)&r1[row * 68 + d];
    float4 s2 = *(const float4*)&r2[row * 68 + d];
    float4 s3 = *(const float4*)&r3[row * 68 + d];
    float4 o;
    o.x = s0.x + s1.x + s2.x + s3.x;
    o.y = s0.y + s1.y + s2.y + s3.y;
    o.z = s0.z + s1.z + s2.z + s3.z;
    o.w = s0.w + s1.w + s2.w + s3.w;
    *(float4*)&ctx[(size_t)(b * N_ + n0 + row) * C_ + h * HD_ + d] = o;
}

// ---------------------------------------------------------------------------
// Kernel 4: proj_mfma (unchanged — validated round 7)
// ---------------------------------------------------------------------------
__global__ __launch_bounds__(256) void proj_mfma(const float* __restrict__ ctx,
                                                 const float* __restrict__ x,
                                                 const _Float16* __restrict__ wp_hi,
                                                 const _Float16* __restrict__ wp_lo,
                                                 const float* __restrict__ bproj,
                                                 float* __restrict__ y) {
    const int tid = threadIdx.x;
    const int lane = tid & 63;
    const int w = tid >> 6;
    const int r16 = lane & 15;
    const int g = lane >> 4;
    const int row0 = blockIdx.x * 32;
    const int colw = blockIdx.y * 128 + w * 32;

    f32x4 acc[2][2] = {};

    const float* ar0 = ctx + (size_t)(row0 + r16) * C_;
    const float* ar1 = ctx + (size_t)(row0 + 16 + r16) * C_;

    for (int kt = 0; kt < 16; kt += 2) {
        float4 a0[2], a1[2], b0[2], b1[2];
#pragma unroll
        for (int u = 0; u < 2; ++u) {
            const int k0 = (kt + u) * 32 + 8 * g;
            a0[u] = *(const float4*)&ar0[k0];
            a1[u] = *(const float4*)&ar0[k0 + 4];
            b0[u] = *(const float4*)&ar1[k0];
            b1[u] = *(const float4*)&ar1[k0 + 4];
        }
#pragma unroll
        for (int u = 0; u < 2; ++u) {
            const int k0 = (kt + u) * 32 + 8 * g;
            f16x8 aHi0, aLo0, aHi1, aLo1;
            cvt_split(a0[u], a1[u], aHi0, aLo0);
            cvt_split(b0[u], b1[u], aHi1, aLo1);
#pragma unroll
            for (int ct = 0; ct < 2; ++ct) {
                const int c = colw + ct * 16 + r16;
                f16x8 bHi = *(const f16x8*)&wp_hi[(size_t)c * C_ + k0];
                f16x8 bLo = *(const f16x8*)&wp_lo[(size_t)c * C_ + k0];
                acc[0][ct] = __builtin_amdgcn_mfma_f32_16x16x32_f16(aHi0, bHi, acc[0][ct], 0, 0, 0);
                acc[0][ct] = __builtin_amdgcn_mfma_f32_16x16x32_f16(aHi0, bLo, acc[0][ct], 0, 0, 0);
                acc[0][ct] = __builtin_amdgcn_mfma_f32_16x16x32_f16(aLo0, bHi, acc[0][ct], 0, 0, 0);
                acc[1][ct] = __builtin_amdgcn_mfma_f32_16x16x32_f16(aHi1, bHi, acc[1][ct], 0, 0, 0);
                acc[1][ct] = __builtin_amdgcn_mfma_f32_16x16x32_f16(aHi1, bLo, acc[1][ct], 0, 0, 0);
                acc[1][ct] = __builtin_amdgcn_mfma_f32_16x16x32_f16(aLo1, bHi, acc[1][ct], 0, 0, 0);
            }
        }
    }

#pragma unroll
    for (int rt = 0; rt < 2; ++rt)
#pragma unroll
        for (int ct = 0; ct < 2; ++ct) {
            const int c = colw + ct * 16 + r16;
            const float bias = bproj[c];
#pragma unroll
            for (int j = 0; j < 4; ++j) {
                const int r = row0 + rt * 16 + 4 * g + j;
                y[(size_t)r * C_ + c] = acc[rt][ct][j] + bias + x[(size_t)r * C_ + c];
            }
        }
}

// ---------------------------------------------------------------------------
// Kernel 5: ln_kernel (unchanged)
// ---------------------------------------------------------------------------
__global__ __launch_bounds__(256) void ln_kernel(float* __restrict__ y,
                                                 const float* __restrict__ gamma,
                                                 const float* __restrict__ beta) {
    __shared__ float wsum[4], wsq[4];
    const int row = blockIdx.x;
    const int tid = threadIdx.x;
    const int lane = tid & 63;
    const int w = tid >> 6;

    float2 v = ((const float2*)(y + (size_t)row * C_))[tid];
    float s = v.x + v.y;
    float sq = v.x * v.x + v.y * v.y;
#pragma unroll
    for (int m = 1; m < 64; m <<= 1) {
        s += __shfl_xor(s, m, 64);
        sq += __shfl_xor(sq, m, 64);
    }
    if (lane == 0) { wsum[w] = s; wsq[w] = sq; }
    __syncthreads();
    float ts = wsum[0] + wsum[1] + wsum[2] + wsum[3];
    float tq = wsq[0] + wsq[1] + wsq[2] + wsq[3];
    float mu = ts * (1.0f / C_);
    float var = tq * (1.0f / C_) - mu * mu;
    float rstd = rsqrtf(var + LN_EPS_);

    float2 g = ((const float2*)gamma)[tid];
    float2 be = ((const float2*)beta)[tid];
    float2 o;
    o.x = (v.x - mu) * rstd * g.x + be.x;
    o.y = (v.y - mu) * rstd * g.y + be.y;
    ((float2*)(y + (size_t)row * C_))[tid] = o;
}

extern "C" void kernel_launch(void* const* d_in, const int* in_sizes, int n_in,
                              void* d_out, int out_size, void* d_ws, size_t ws_size,
                              hipStream_t stream) {
    const float* x     = (const float*)d_in[0];
    const float* Wqkv  = (const float*)d_in[1];
    const float* bqkv  = (const float*)d_in[2];
    const float* ow    = (const float*)d_in[3];
    const float* Wproj = (const float*)d_in[4];
    const float* bproj = (const float*)d_in[5];
    const float* gamma = (const float*)d_in[6];
    const float* beta  = (const float*)d_in[7];

    float* out  = (float*)d_out;
    float* y    = out;                                  // [B,N,C]
    float* attn = out + (size_t)B_ * N_ * C_;           // [B,H,N,N]
    float* qkv  = (float*)d_ws;                         // [B*N, 3C]  25 MB
    float* ctx  = qkv + (size_t)B_ * N_ * 3 * C_;       // [B*N, C]    8 MB

    // Wt_hi/Wt_lo overlay the attn output region (3 MB of 128 MB); consumed by
    // qkv_gemm_mfma, then rewritten by attn_scores.
    _Float16* wt_hi = (_Float16*)attn;
    _Float16* wt_lo = wt_hi + (size_t)(3 * C_) * C_;
    // Vt_hi/Vt_lo overlay the y region (8 MB exactly); consumed by attn_scores
    // (fused PV), then rewritten by proj_mfma.
    _Float16* vt_hi = (_Float16*)y;
    _Float16* vt_lo = vt_hi + (size_t)B_ * H_ * HD_ * N_;
    // wp_hi/wp_lo live in the ws tail after ctx (1 MB; ws is much larger).
    _Float16* wp_hi = (_Float16*)(ctx + (size_t)B_ * N_ * C_);
    _Float16* wp_lo = wp_hi + (size_t)C_ * C_;

    dim3 g0(3 * C_ / 64, C_ / 64);                      // (24, 8)
    wsplit_qkv<<<g0, 256, 0, stream>>>(Wqkv, wt_hi, wt_lo);

    dim3 gp(C_ / 64, C_ / 64);                          // (8, 8)
    wsplit_proj<<<gp, 256, 0, stream>>>(Wproj, wp_hi, wp_lo);

    dim3 g1(B_ * N_ / 32, 3 * C_ / 256);                // (128, 6)
    qkv_gemm_mfma<<<g1, 256, 0, stream>>>(x, wt_hi, wt_lo, bqkv, qkv);

    dim3 gv(N_ / 64, B_ * H_);                          // (16, 32)
    vsplit_v<<<gv, 256, 0, stream>>>(qkv, vt_hi, vt_lo);

    dim3 g2(N_ / 16, B_ * H_);                          // (64, 32)
    attn_scores<<<g2, 256, 0, stream>>>(qkv, ow, vt_hi, vt_lo, attn, ctx);

    dim3 g4(B_ * N_ / 32, C_ / 128);                    // (128, 4)
    proj_mfma<<<g4, 256, 0, stream>>>(ctx, x, wp_hi, wp_lo, bproj, y);

    ln_kernel<<<B_ * N_, 256, 0, stream>>>(y, gamma, beta);
}

// Round 12
// 380.348 us; speedup vs baseline: 1.1108x; 1.0044x over previous
//
#include <hip/hip_runtime.h>
#include <math.h>

#define B_ 4
#define N_ 1024
#define C_ 512
#define H_ 8
#define HD_ 64
#define SCALE_ 0.125f
#define LN_EPS_ 1e-5f

typedef _Float16 f16x8 __attribute__((ext_vector_type(8)));
typedef float f32x4 __attribute__((ext_vector_type(4)));

// Split 8 fp32 (two float4) into f16 hi + f16 lo such that hi+lo ~= x (22-bit).
__device__ __forceinline__ void cvt_split(const float4& A, const float4& Bv,
                                          f16x8& hi, f16x8& lo) {
    float v[8] = {A.x, A.y, A.z, A.w, Bv.x, Bv.y, Bv.z, Bv.w};
#pragma unroll
    for (int i = 0; i < 8; ++i) {
        _Float16 h = (_Float16)v[i];
        hi[i] = h;
        lo[i] = (_Float16)(v[i] - (float)h);
    }
}

// ---------------------------------------------------------------------------
// Kernel 0: wsplit_qkv — transpose + f16-split Wqkv [512][1536] into
//   Wt_hi/Wt_lo [1536][512]. Lives in attn region (rewritten by attn_scores).
// ---------------------------------------------------------------------------
__global__ __launch_bounds__(256) void wsplit_qkv(const float* __restrict__ W,
                                                  _Float16* __restrict__ wt_hi,
                                                  _Float16* __restrict__ wt_lo) {
    __shared__ float tile[64][65];
    const int tid = threadIdx.x;
    const int n0 = blockIdx.x * 64;   // col of W  (row of Wt)
    const int k0 = blockIdx.y * 64;   // row of W  (col of Wt)
#pragma unroll
    for (int i = 0; i < 16; ++i) {
        int e = tid + i * 256;
        int kk = e >> 6, nn = e & 63;
        tile[kk][nn] = W[(size_t)(k0 + kk) * (3 * C_) + n0 + nn];
    }
    __syncthreads();
#pragma unroll
    for (int i = 0; i < 16; ++i) {
        int e = tid + i * 256;
        int n = e >> 6, k = e & 63;
        float v = tile[k][n];
        _Float16 h = (_Float16)v;
        wt_hi[(size_t)(n0 + n) * C_ + k0 + k] = h;
        wt_lo[(size_t)(n0 + n) * C_ + k0 + k] = (_Float16)(v - (float)h);
    }
}

// ---------------------------------------------------------------------------
// Kernel 0c: wsplit_proj — transpose + f16-split Wproj [512][512] into
//   wp_hi/wp_lo [512][512]. Lives in ws tail.
// ---------------------------------------------------------------------------
__global__ __launch_bounds__(256) void wsplit_proj(const float* __restrict__ W,
                                                   _Float16* __restrict__ wp_hi,
                                                   _Float16* __restrict__ wp_lo) {
    __shared__ float tile[64][65];
    const int tid = threadIdx.x;
    const int n0 = blockIdx.x * 64;
    const int k0 = blockIdx.y * 64;
#pragma unroll
    for (int i = 0; i < 16; ++i) {
        int e = tid + i * 256;
        int kk = e >> 6, nn = e & 63;
        tile[kk][nn] = W[(size_t)(k0 + kk) * C_ + n0 + nn];
    }
    __syncthreads();
#pragma unroll
    for (int i = 0; i < 16; ++i) {
        int e = tid + i * 256;
        int n = e >> 6, k = e & 63;
        float v = tile[k][n];
        _Float16 h = (_Float16)v;
        wp_hi[(size_t)(n0 + n) * C_ + k0 + k] = h;
        wp_lo[(size_t)(n0 + n) * C_ + k0 + k] = (_Float16)(v - (float)h);
    }
}

// ---------------------------------------------------------------------------
// Kernel 0b: vsplit_v — transpose + f16-split V (from qkv) into
//   Vt_hi/Vt_lo [B*H][HD][N]. Lives in y region (rewritten by proj_mfma).
// ---------------------------------------------------------------------------
__global__ __launch_bounds__(256) void vsplit_v(const float* __restrict__ qkv,
                                                _Float16* __restrict__ vt_hi,
                                                _Float16* __restrict__ vt_lo) {
    __shared__ float tile[64][65];
    const int tid = threadIdx.x;
    const int m0 = blockIdx.x * 64;
    const int bh = blockIdx.y;
    const int b = bh >> 3, h = bh & 7;
    const size_t RS = 3 * C_;
#pragma unroll
    for (int i = 0; i < 16; ++i) {
        int e = tid + i * 256;
        int mm = e >> 6, d = e & 63;
        tile[mm][d] = qkv[(size_t)(b * N_ + m0 + mm) * RS + 2 * C_ + h * HD_ + d];
    }
    __syncthreads();
#pragma unroll
    for (int i = 0; i < 16; ++i) {
        int e = tid + i * 256;
        int d = e >> 6, mm = e & 63;
        float v = tile[mm][d];
        _Float16 hh = (_Float16)v;
        size_t idx = ((size_t)bh * HD_ + d) * N_ + m0 + mm;
        vt_hi[idx] = hh;
        vt_lo[idx] = (_Float16)(v - (float)hh);
    }
}

// ---------------------------------------------------------------------------
// Kernel 1: qkv_gemm_mfma (unchanged — validated round 3)
// ---------------------------------------------------------------------------
__global__ __launch_bounds__(256) void qkv_gemm_mfma(const float* __restrict__ x,
                                                     const _Float16* __restrict__ wt_hi,
                                                     const _Float16* __restrict__ wt_lo,
                                                     const float* __restrict__ bqkv,
                                                     float* __restrict__ qkv) {
    const int tid = threadIdx.x;
    const int lane = tid & 63;
    const int w = tid >> 6;
    const int r16 = lane & 15;
    const int g = lane >> 4;
    const int row0 = blockIdx.x * 32;
    const int col0 = blockIdx.y * 256 + w * 64;

    f32x4 acc[2][4] = {};

    const float* xr0 = x + (size_t)(row0 + r16) * C_;
    const float* xr1 = x + (size_t)(row0 + 16 + r16) * C_;

    for (int kt = 0; kt < 16; ++kt) {
        const int k0 = kt * 32 + 8 * g;
        f16x8 aHi0, aLo0, aHi1, aLo1;
        {
            float4 a0 = *(const float4*)&xr0[k0];
            float4 a1 = *(const float4*)&xr0[k0 + 4];
            cvt_split(a0, a1, aHi0, aLo0);
            float4 b0 = *(const float4*)&xr1[k0];
            float4 b1 = *(const float4*)&xr1[k0 + 4];
            cvt_split(b0, b1, aHi1, aLo1);
        }
#pragma unroll
        for (int ct = 0; ct < 4; ++ct) {
            const int c = col0 + ct * 16 + r16;
            f16x8 bHi = *(const f16x8*)&wt_hi[(size_t)c * C_ + k0];
            f16x8 bLo = *(const f16x8*)&wt_lo[(size_t)c * C_ + k0];
            acc[0][ct] = __builtin_amdgcn_mfma_f32_16x16x32_f16(aHi0, bHi, acc[0][ct], 0, 0, 0);
            acc[0][ct] = __builtin_amdgcn_mfma_f32_16x16x32_f16(aHi0, bLo, acc[0][ct], 0, 0, 0);
            acc[0][ct] = __builtin_amdgcn_mfma_f32_16x16x32_f16(aLo0, bHi, acc[0][ct], 0, 0, 0);
            acc[1][ct] = __builtin_amdgcn_mfma_f32_16x16x32_f16(aHi1, bHi, acc[1][ct], 0, 0, 0);
            acc[1][ct] = __builtin_amdgcn_mfma_f32_16x16x32_f16(aHi1, bLo, acc[1][ct], 0, 0, 0);
            acc[1][ct] = __builtin_amdgcn_mfma_f32_16x16x32_f16(aLo1, bHi, acc[1][ct], 0, 0, 0);
        }
    }

#pragma unroll
    for (int rt = 0; rt < 2; ++rt)
#pragma unroll
        for (int ct = 0; ct < 4; ++ct) {
            const int c = col0 + ct * 16 + r16;
            const float bias = bqkv[c];
#pragma unroll
            for (int j = 0; j < 4; ++j) {
                const int r = row0 + rt * 16 + 4 * g + j;
                qkv[(size_t)r * (3 * C_) + c] = acc[rt][ct][j] + bias;
            }
        }
}

// ---------------------------------------------------------------------------
// Kernel 2: attn_scores — fused QK^T + polynomial + softmax + PV.
//   Round-12 change: phase-1 K loads hoisted 4-t-deep (16 float4 in flight,
//   round-6-validated MLP pattern). VGPR=72 previously proved the compiler
//   serialized each t's loads — 16 full latency exposures per wave.
// ---------------------------------------------------------------------------
__global__ __launch_bounds__(256) void attn_scores(const float* __restrict__ qkv,
                                                   const float* __restrict__ ow_in,
                                                   const _Float16* __restrict__ vt_hi,
                                                   const _Float16* __restrict__ vt_lo,
                                                   float* __restrict__ attn,
                                                   float* __restrict__ ctx) {
    __shared__ float smax[4][16];
    __shared__ float ssum[4][16];
    __shared__ float Pw[4][16][140];   // per-wave private; 140 = 128 + 12 pad

    const int tid = threadIdx.x;
    const int lane = tid & 63;
    const int w = tid >> 6;           // wave 0..3 -> key cols [w*256, w*256+256)
    const int r16 = lane & 15;        // A row / B col / D col
    const int g = lane >> 4;          // k-group
    const int n0 = blockIdx.x * 16;   // query-row tile
    const int bh = blockIdx.y;
    const int b = bh >> 3, h = bh & 7;
    const size_t RS = 3 * C_;

    float w0 = ow_in[0], w1 = ow_in[1], w2 = ow_in[2];
    float wm = fmaxf(w0, fmaxf(w1, w2));
    float e0 = __expf(w0 - wm), e1 = __expf(w1 - wm), e2 = __expf(w2 - wm);
    float einv = 1.0f / (e0 + e1 + e2);
    float ow0 = e0 * einv, ow1 = e1 * einv, ow2 = e2 * einv;

    const float* qrow = qkv + (size_t)(b * N_ + n0 + r16) * RS + h * HD_;
    f16x8 aHi0, aLo0, aHi1, aLo1;
    {
        float4 qa = ((const float4*)qrow)[2 * g + 0];
        float4 qb = ((const float4*)qrow)[2 * g + 1];
        float4 qc = ((const float4*)qrow)[8 + 2 * g];
        float4 qd = ((const float4*)qrow)[9 + 2 * g];
        cvt_split(qa, qb, aHi0, aLo0);
        cvt_split(qc, qd, aHi1, aLo1);
    }

    float p[16][4];

    const float* kbase = qkv + (size_t)(b * N_) * RS + C_ + h * HD_;
#pragma unroll
    for (int tb = 0; tb < 4; ++tb) {
        // ---- issue all 16 K loads for 4 t-iterations up front (MLP) ----
        float4 kq0[4], kq1[4], kq2[4], kq3[4];
#pragma unroll
        for (int u = 0; u < 4; ++u) {
            const int ct = w * 16 + tb * 4 + u;
            const float* krow = kbase + (size_t)(ct * 16 + r16) * RS;
            kq0[u] = ((const float4*)krow)[2 * g + 0];
            kq1[u] = ((const float4*)krow)[2 * g + 1];
            kq2[u] = ((const float4*)krow)[8 + 2 * g];
            kq3[u] = ((const float4*)krow)[9 + 2 * g];
        }
#pragma unroll
        for (int u = 0; u < 4; ++u) {
            const int t = tb * 4 + u;
            f16x8 bHi0, bLo0, bHi1, bLo1;
            cvt_split(kq0[u], kq1[u], bHi0, bLo0);
            cvt_split(kq2[u], kq3[u], bHi1, bLo1);

            f32x4 acc = {0.f, 0.f, 0.f, 0.f};
            acc = __builtin_amdgcn_mfma_f32_16x16x32_f16(aHi0, bHi0, acc, 0, 0, 0);
            acc = __builtin_amdgcn_mfma_f32_16x16x32_f16(aHi0, bLo0, acc, 0, 0, 0);
            acc = __builtin_amdgcn_mfma_f32_16x16x32_f16(aLo0, bHi0, acc, 0, 0, 0);
            acc = __builtin_amdgcn_mfma_f32_16x16x32_f16(aHi1, bHi1, acc, 0, 0, 0);
            acc = __builtin_amdgcn_mfma_f32_16x16x32_f16(aHi1, bLo1, acc, 0, 0, 0);
            acc = __builtin_amdgcn_mfma_f32_16x16x32_f16(aLo1, bHi1, acc, 0, 0, 0);

#pragma unroll
            for (int j = 0; j < 4; ++j) {
                float s = acc[j] * SCALE_;
                p[t][j] = s * (ow0 + s * (ow1 + s * ow2));
            }
        }
    }

    float rmax[4] = {-1e30f, -1e30f, -1e30f, -1e30f};
#pragma unroll
    for (int t = 0; t < 16; ++t)
#pragma unroll
        for (int j = 0; j < 4; ++j) rmax[j] = fmaxf(rmax[j], p[t][j]);
#pragma unroll
    for (int j = 0; j < 4; ++j)
#pragma unroll
        for (int m = 1; m < 16; m <<= 1)
            rmax[j] = fmaxf(rmax[j], __shfl_xor(rmax[j], m, 64));
    if (r16 == 0) {
#pragma unroll
        for (int j = 0; j < 4; ++j) smax[w][g * 4 + j] = rmax[j];
    }
    __syncthreads();
    float gm[4];
#pragma unroll
    for (int j = 0; j < 4; ++j) {
        int rr = g * 4 + j;
        gm[j] = fmaxf(fmaxf(smax[0][rr], smax[1][rr]),
                      fmaxf(smax[2][rr], smax[3][rr]));
    }

    float rsum[4] = {0.f, 0.f, 0.f, 0.f};
#pragma unroll
    for (int t = 0; t < 16; ++t)
#pragma unroll
        for (int j = 0; j < 4; ++j) {
            float e = __expf(p[t][j] - gm[j]);
            p[t][j] = e;
            rsum[j] += e;
        }
#pragma unroll
    for (int j = 0; j < 4; ++j)
#pragma unroll
        for (int m = 1; m < 16; m <<= 1)
            rsum[j] += __shfl_xor(rsum[j], m, 64);
    if (r16 == 0) {
#pragma unroll
        for (int j = 0; j < 4; ++j) ssum[w][g * 4 + j] = rsum[j];
    }
    __syncthreads();
    float inv[4];
#pragma unroll
    for (int j = 0; j < 4; ++j) {
        int rr = g * 4 + j;
        inv[j] = 1.0f / (ssum[0][rr] + ssum[1][rr] + ssum[2][rr] + ssum[3][rr]);
    }

    // normalize in-register: p becomes the final probabilities
#pragma unroll
    for (int t = 0; t < 16; ++t)
#pragma unroll
        for (int j = 0; j < 4; ++j)
            p[t][j] *= inv[j];

    // ---- Phase 2: PV + coalesced attn store via per-wave LDS transpose ----
    const _Float16* vh = vt_hi + (size_t)bh * HD_ * N_ + w * 256 + 8 * g;
    const _Float16* vl = vt_lo + (size_t)bh * HD_ * N_ + w * 256 + 8 * g;
    float* pw = &Pw[w][0][0];          // this wave's private region

    f32x4 acc[4] = {};

#pragma unroll
    for (int half = 0; half < 2; ++half) {
        // transpose 8 t-tiles (128 keys) into [16 rows][140]
#pragma unroll
        for (int t8 = 0; t8 < 8; ++t8) {
            const int t = half * 8 + t8;
#pragma unroll
            for (int j = 0; j < 4; ++j)
                pw[(4 * g + j) * 140 + t8 * 16 + r16] = p[t][j];
        }
        // consume: 4 MFMA k-steps of 32 keys
#pragma unroll
        for (int kk = 0; kk < 4; ++kk) {
            float4 q0 = *(const float4*)&pw[r16 * 140 + kk * 32 + 8 * g];
            float4 q1 = *(const float4*)&pw[r16 * 140 + kk * 32 + 8 * g + 4];
            f16x8 aHi, aLo;
            cvt_split(q0, q1, aHi, aLo);
            const int kb = half * 128 + kk * 32;
#pragma unroll
            for (int ct = 0; ct < 4; ++ct) {
                const int d = ct * 16 + r16;
                f16x8 bHi = *(const f16x8*)&vh[(size_t)d * N_ + kb];
                f16x8 bLo = *(const f16x8*)&vl[(size_t)d * N_ + kb];
                acc[ct] = __builtin_amdgcn_mfma_f32_16x16x32_f16(aHi, bHi, acc[ct], 0, 0, 0);
                acc[ct] = __builtin_amdgcn_mfma_f32_16x16x32_f16(aHi, bLo, acc[ct], 0, 0, 0);
                acc[ct] = __builtin_amdgcn_mfma_f32_16x16x32_f16(aLo, bHi, acc[ct], 0, 0, 0);
            }
        }
        // coalesced attn store of this half from LDS:
        // Pw[row][c] == attn[n0+row][w*256 + half*128 + c]
#pragma unroll
        for (int it = 0; it < 8; ++it) {
            const int f = it * 64 + lane;      // float4 index in 16x128 tile
            const int row = f >> 5;             // 0..15
            const int c4 = (f & 31) * 4;        // 0..124
            float4 v4 = *(const float4*)&pw[row * 140 + c4];
            *(float4*)&attn[((size_t)bh * N_ + n0 + row) * N_ + w * 256 + half * 128 + c4] = v4;
        }
    }

    // partials into own region (reuse pw; own reads are done in program order)
#pragma unroll
    for (int ct = 0; ct < 4; ++ct)
#pragma unroll
        for (int j = 0; j < 4; ++j)
            pw[(4 * g + j) * 68 + ct * 16 + r16] = acc[ct][j];
    __syncthreads();

    // cross-wave reduce + coalesced float4 store (pv-v3 epilogue)
    const int e = tid * 4;
    const int row = e >> 6;
    const int d = e & 63;
    const float* r0 = &Pw[0][0][0];
    const float* r1 = &Pw[1][0][0];
    const float* r2 = &Pw[2][0][0];
    const float* r3 = &Pw[3][0][0];
    float4 s0 = *(const float4*)&r0[row * 68 + d];
    float4 s1 = *(const float4*)&r1[row * 68 + d];
    float4 s2 = *(const float4*)&r2[row * 68 + d];
    float4 s3 = *(const float4*)&r3[row * 68 + d];
    float4 o;
    o.x = s0.x + s1.x + s2.x + s3.x;
    o.y = s0.y + s1.y + s2.y + s3.y;
    o.z = s0.z + s1.z + s2.z + s3.z;
    o.w = s0.w + s1.w + s2.w + s3.w;
    *(float4*)&ctx[(size_t)(b * N_ + n0 + row) * C_ + h * HD_ + d] = o;
}

// ---------------------------------------------------------------------------
// Kernel 4: proj_mfma (unchanged — validated round 7)
// ---------------------------------------------------------------------------
__global__ __launch_bounds__(256) void proj_mfma(const float* __restrict__ ctx,
                                                 const float* __restrict__ x,
                                                 const _Float16* __restrict__ wp_hi,
                                                 const _Float16* __restrict__ wp_lo,
                                                 const float* __restrict__ bproj,
                                                 float* __restrict__ y) {
    const int tid = threadIdx.x;
    const int lane = tid & 63;
    const int w = tid >> 6;
    const int r16 = lane & 15;
    const int g = lane >> 4;
    const int row0 = blockIdx.x * 32;
    const int colw = blockIdx.y * 128 + w * 32;

    f32x4 acc[2][2] = {};

    const float* ar0 = ctx + (size_t)(row0 + r16) * C_;
    const float* ar1 = ctx + (size_t)(row0 + 16 + r16) * C_;

    for (int kt = 0; kt < 16; kt += 2) {
        float4 a0[2], a1[2], b0[2], b1[2];
#pragma unroll
        for (int u = 0; u < 2; ++u) {
            const int k0 = (kt + u) * 32 + 8 * g;
            a0[u] = *(const float4*)&ar0[k0];
            a1[u] = *(const float4*)&ar0[k0 + 4];
            b0[u] = *(const float4*)&ar1[k0];
            b1[u] = *(const float4*)&ar1[k0 + 4];
        }
#pragma unroll
        for (int u = 0; u < 2; ++u) {
            const int k0 = (kt + u) * 32 + 8 * g;
            f16x8 aHi0, aLo0, aHi1, aLo1;
            cvt_split(a0[u], a1[u], aHi0, aLo0);
            cvt_split(b0[u], b1[u], aHi1, aLo1);
#pragma unroll
            for (int ct = 0; ct < 2; ++ct) {
                const int c = colw + ct * 16 + r16;
                f16x8 bHi = *(const f16x8*)&wp_hi[(size_t)c * C_ + k0];
                f16x8 bLo = *(const f16x8*)&wp_lo[(size_t)c * C_ + k0];
                acc[0][ct] = __builtin_amdgcn_mfma_f32_16x16x32_f16(aHi0, bHi, acc[0][ct], 0, 0, 0);
                acc[0][ct] = __builtin_amdgcn_mfma_f32_16x16x32_f16(aHi0, bLo, acc[0][ct], 0, 0, 0);
                acc[0][ct] = __builtin_amdgcn_mfma_f32_16x16x32_f16(aLo0, bHi, acc[0][ct], 0, 0, 0);
                acc[1][ct] = __builtin_amdgcn_mfma_f32_16x16x32_f16(aHi1, bHi, acc[1][ct], 0, 0, 0);
                acc[1][ct] = __builtin_amdgcn_mfma_f32_16x16x32_f16(aHi1, bLo, acc[1][ct], 0, 0, 0);
                acc[1][ct] = __builtin_amdgcn_mfma_f32_16x16x32_f16(aLo1, bHi, acc[1][ct], 0, 0, 0);
            }
        }
    }

#pragma unroll
    for (int rt = 0; rt < 2; ++rt)
#pragma unroll
        for (int ct = 0; ct < 2; ++ct) {
            const int c = colw + ct * 16 + r16;
            const float bias = bproj[c];
#pragma unroll
            for (int j = 0; j < 4; ++j) {
                const int r = row0 + rt * 16 + 4 * g + j;
                y[(size_t)r * C_ + c] = acc[rt][ct][j] + bias + x[(size_t)r * C_ + c];
            }
        }
}

// ---------------------------------------------------------------------------
// Kernel 5: ln_kernel (unchanged)
// ---------------------------------------------------------------------------
__global__ __launch_bounds__(256) void ln_kernel(float* __restrict__ y,
                                                 const float* __restrict__ gamma,
                                                 const float* __restrict__ beta) {
    __shared__ float wsum[4], wsq[4];
    const int row = blockIdx.x;
    const int tid = threadIdx.x;
    const int lane = tid & 63;
    const int w = tid >> 6;

    float2 v = ((const float2*)(y + (size_t)row * C_))[tid];
    float s = v.x + v.y;
    float sq = v.x * v.x + v.y * v.y;
#pragma unroll
    for (int m = 1; m < 64; m <<= 1) {
        s += __shfl_xor(s, m, 64);
        sq += __shfl_xor(sq, m, 64);
    }
    if (lane == 0) { wsum[w] = s; wsq[w] = sq; }
    __syncthreads();
    float ts = wsum[0] + wsum[1] + wsum[2] + wsum[3];
    float tq = wsq[0] + wsq[1] + wsq[2] + wsq[3];
    float mu = ts * (1.0f / C_);
    float var = tq * (1.0f / C_) - mu * mu;
    float rstd = rsqrtf(var + LN_EPS_);

    float2 g = ((const float2*)gamma)[tid];
    float2 be = ((const float2*)beta)[tid];
    float2 o;
    o.x = (v.x - mu) * rstd * g.x + be.x;
    o.y = (v.y - mu) * rstd * g.y + be.y;
    ((float2*)(y + (size_t)row * C_))[tid] = o;
}

extern "C" void kernel_launch(void* const* d_in, const int* in_sizes, int n_in,
                              void* d_out, int out_size, void* d_ws, size_t ws_size,
                              hipStream_t stream) {
    const float* x     = (const float*)d_in[0];
    const float* Wqkv  = (const float*)d_in[1];
    const float* bqkv  = (const float*)d_in[2];
    const float* ow    = (const float*)d_in[3];
    const float* Wproj = (const float*)d_in[4];
    const float* bproj = (const float*)d_in[5];
    const float* gamma = (const float*)d_in[6];
    const float* beta  = (const float*)d_in[7];

    float* out  = (float*)d_out;
    float* y    = out;                                  // [B,N,C]
    float* attn = out + (size_t)B_ * N_ * C_;           // [B,H,N,N]
    float* qkv  = (float*)d_ws;                         // [B*N, 3C]  25 MB
    float* ctx  = qkv + (size_t)B_ * N_ * 3 * C_;       // [B*N, C]    8 MB

    // Wt_hi/Wt_lo overlay the attn output region (3 MB of 128 MB); consumed by
    // qkv_gemm_mfma, then rewritten by attn_scores.
    _Float16* wt_hi = (_Float16*)attn;
    _Float16* wt_lo = wt_hi + (size_t)(3 * C_) * C_;
    // Vt_hi/Vt_lo overlay the y region (8 MB exactly); consumed by attn_scores
    // (fused PV), then rewritten by proj_mfma.
    _Float16* vt_hi = (_Float16*)y;
    _Float16* vt_lo = vt_hi + (size_t)B_ * H_ * HD_ * N_;
    // wp_hi/wp_lo live in the ws tail after ctx (1 MB; ws is much larger).
    _Float16* wp_hi = (_Float16*)(ctx + (size_t)B_ * N_ * C_);
    _Float16* wp_lo = wp_hi + (size_t)C_ * C_;

    dim3 g0(3 * C_ / 64, C_ / 64);                      // (24, 8)
    wsplit_qkv<<<g0, 256, 0, stream>>>(Wqkv, wt_hi, wt_lo);

    dim3 gp(C_ / 64, C_ / 64);                          // (8, 8)
    wsplit_proj<<<gp, 256, 0, stream>>>(Wproj, wp_hi, wp_lo);

    dim3 g1(B_ * N_ / 32, 3 * C_ / 256);                // (128, 6)
    qkv_gemm_mfma<<<g1, 256, 0, stream>>>(x, wt_hi, wt_lo, bqkv, qkv);

    dim3 gv(N_ / 64, B_ * H_);                          // (16, 32)
    vsplit_v<<<gv, 256, 0, stream>>>(qkv, vt_hi, vt_lo);

    dim3 g2(N_ / 16, B_ * H_);                          // (64, 32)
    attn_scores<<<g2, 256, 0, stream>>>(qkv, ow, vt_hi, vt_lo, attn, ctx);

    dim3 g4(B_ * N_ / 32, C_ / 128);                    // (128, 4)
    proj_mfma<<<g4, 256, 0, stream>>>(ctx, x, wp_hi, wp_lo, bproj, y);

    ln_kernel<<<B_ * N_, 256, 0, stream>>>(y, gamma, beta);
}